// Round 6
// baseline (248.357 us; speedup 1.0000x reference)
//
#include <hip/hip_runtime.h>

// Deformable conv2d (N=4, C=OC=256, 80x80, 3x3, s1 p1 d1):
// fused bilinear-im2col + bf16 MFMA GEMM, fp32 accumulate.
// R6: R3 structure (channel-inner k, 800 blocks, no split-K, direct stores)
//     but 512-thread / 8-wave blocks: same grid -> 24 waves/CU resident
//     (vs 12), doubling latency-hiding for the scattered bilinear gathers.

typedef short short8 __attribute__((ext_vector_type(8)));
typedef short short4v __attribute__((ext_vector_type(4)));
typedef float floatx4 __attribute__((ext_vector_type(4)));
typedef float floatx2 __attribute__((ext_vector_type(2)));

#define Cc    256
#define OCc   256
#define Hh    80
#define Ww    80
#define HW    6400
#define KK    9
#define Ktot  2304
#define PT    32            // pixels per block
#define KC    64            // K per chunk
#define NCHUNK (Ktot / KC)  // 36
#define NKB   (Ktot / 32)   // 72

__device__ __forceinline__ unsigned short f2bf(float f) {
  unsigned u = __float_as_uint(f);
  u += 0x7FFF + ((u >> 16) & 1);
  return (unsigned short)(u >> 16);
}

// ---- Kernel 1: weight fp32 -> bf16 in MFMA A-fragment order ----
__global__ void pack_weight(const float* __restrict__ w,
                            unsigned short* __restrict__ wp) {
  const int t = blockIdx.x * 256 + threadIdx.x;   // 73728 threads
  const int lane = t & 63;
  const int ocf  = (t >> 6) & 15;
  const int kb   = t >> 10;
  const int oc   = ocf * 16 + (lane & 15);
  const int k0   = kb * 32 + (lane >> 4) * 8;
  const float* src = w + (size_t)oc * Ktot + k0;
  short8 pk;
  #pragma unroll
  for (int e = 0; e < 8; ++e) pk[e] = (short)f2bf(src[e]);
  *(short8*)(wp + (size_t)t * 8) = pk;
}

// ---- Kernel 2: fused sampling + MFMA, 8 waves/block ----
__global__ __launch_bounds__(512, 8) void dcn_mfma(
    const float* __restrict__ x, const float* __restrict__ offset,
    const unsigned short* __restrict__ wp, float* __restrict__ out) {
  __shared__ unsigned short s_col[2][PT * KC];  // 2 x 4KB, XOR-swizzled [px][k]
  __shared__ float4 s_w[KK * PT];               // corner weights (pre-swapped)
  __shared__ int2   s_i[KK * PT];               // paired-corner row bases

  const int tid  = threadIdx.x;
  const int lane = tid & 63;
  const int wv   = tid >> 6;        // 8 waves; wave owns oc [wv*32, wv*32+32)
  const int n    = blockIdx.y;
  const int p0   = blockIdx.x * PT;

  // ---- Phase 0: bilinear coords; edge handling folded into weights ----
  if (tid < KK * PT) {
    const int s = tid;
    const int k = s / PT, p = s % PT;
    const int pp = p0 + p;
    const int oy = pp / Ww, ox = pp % Ww;
    const int ky = k / 3, kx = k % 3;
    const float offy = offset[(size_t)(n * 18 + 2 * k    ) * HW + pp];
    const float offx = offset[(size_t)(n * 18 + 2 * k + 1) * HW + pp];
    const float py = offy + (float)(ky + oy - 1);
    const float px = offx + (float)(kx + ox - 1);
    const float fy0 = floorf(py), fx0 = floorf(px);
    const int iy0 = (int)fy0, ix0 = (int)fx0;
    const float wy1 = py - fy0, wx1 = px - fx0;
    const float wy0 = 1.f - wy1, wx0 = 1.f - wx1;
    const bool my0 = (iy0     >= 0) & (iy0     < Hh);
    const bool my1 = (iy0 + 1 >= 0) & (iy0 + 1 < Hh);
    const bool mx0 = (ix0     >= 0) & (ix0     < Ww);
    const bool mx1 = (ix0 + 1 >= 0) & (ix0 + 1 < Ww);
    const int cy0 = min(max(iy0,     0), Hh - 1);
    const int cy1 = min(max(iy0 + 1, 0), Hh - 1);
    const int bx  = min(max(ix0, 0), Ww - 2);   // dwordx2 base: [bx, bx+1]
    const bool sel = (ix0 == bx);
    const float wa = wx0 * wy0 * ((my0 && mx0) ? 1.f : 0.f);
    const float wb = wx1 * wy0 * ((my0 && mx1) ? 1.f : 0.f);
    const float wc = wx0 * wy1 * ((my1 && mx0) ? 1.f : 0.f);
    const float wd = wx1 * wy1 * ((my1 && mx1) ? 1.f : 0.f);
    float4 w4;  // pair-swap when x0 clamped off-base (masks make it exact)
    w4.x = sel ? wa : wb;  w4.y = sel ? wb : wa;
    w4.z = sel ? wc : wd;  w4.w = sel ? wd : wc;
    s_w[s] = w4;
    s_i[s] = make_int2(cy0 * Ww + bx, cy1 * Ww + bx);
  }

  floatx4 acc[2][2] = {};           // 2 oc-frags x 2 px-frags
  const int lm = lane & 15, lg = lane >> 4;
  const int spx  = tid & 31;        // sampling pixel
  const int skc0 = (tid >> 5) * 4;  // 4 consecutive k per thread
  __syncthreads();

  // ---- Prologue: sample chunk 0 into buffer 0 ----
  {
    floatx2 ga[4], gb[4];
    #pragma unroll
    for (int i = 0; i < 4; ++i) {
      const int kg = skc0 + i;
      const int c = kg / 9, tap = kg - c * 9;
      const int2 o2 = s_i[tap * PT + spx];
      const float* xp = x + (size_t)(n * Cc + c) * HW;
      ga[i] = *(const floatx2*)(xp + o2.x);
      gb[i] = *(const floatx2*)(xp + o2.y);
    }
    short4v pk;
    #pragma unroll
    for (int i = 0; i < 4; ++i) {
      const int kg = skc0 + i;
      const int c = kg / 9, tap = kg - c * 9;
      const float4 w4 = s_w[tap * PT + spx];
      const float v = w4.x * ga[i].x + w4.y * ga[i].y
                    + w4.z * gb[i].x + w4.w * gb[i].y;
      pk[i] = (short)f2bf(v);
    }
    const int byte = spx * 128 + ((skc0 * 2) ^ ((spx & 7) << 4));
    *(short4v*)((char*)s_col[0] + byte) = pk;   // aligned 8B, XOR-constant span
  }
  __syncthreads();

  // ---- Main pipeline over 36 chunks ----
  for (int ch = 0; ch < NCHUNK; ++ch) {
    const int cur = ch & 1;
    const bool more = (ch + 1 < NCHUNK);

    // 1) issue next chunk's gathers -> registers (hide under MFMA)
    floatx2 ga[4], gb[4];
    if (more) {
      const int c0n = (ch + 1) * KC;
      #pragma unroll
      for (int i = 0; i < 4; ++i) {
        const int kg = c0n + skc0 + i;
        const int c = kg / 9, tap = kg - c * 9;
        const int2 o2 = s_i[tap * PT + spx];
        const float* xp = x + (size_t)(n * Cc + c) * HW;
        ga[i] = *(const floatx2*)(xp + o2.x);
        gb[i] = *(const floatx2*)(xp + o2.y);
      }
    }

    // 2) MFMA on current buffer: wave wv -> oc-frags {wv*2, wv*2+1}
    const int kb0 = ch * 2;
    #pragma unroll
    for (int ks = 0; ks < 2; ++ks) {
      short8 b[2];
      #pragma unroll
      for (int j = 0; j < 2; ++j) {
        const int px = j * 16 + lm;
        const int byte = px * 128 + (((ks * 64) + lg * 16) ^ ((px & 7) << 4));
        b[j] = *(const short8*)((const char*)s_col[cur] + byte);
      }
      const size_t abase = (size_t)(kb0 + ks) * 16 * 64 * 8;
      #pragma unroll
      for (int f = 0; f < 2; ++f) {
        const int ocf = wv * 2 + f;
        const short8 a = *(const short8*)(wp + abase + (size_t)(ocf * 64 + lane) * 8);
        acc[f][0] = __builtin_amdgcn_mfma_f32_16x16x32_bf16(a, b[0], acc[f][0], 0, 0, 0);
        acc[f][1] = __builtin_amdgcn_mfma_f32_16x16x32_bf16(a, b[1], acc[f][1], 0, 0, 0);
      }
    }

    // 3) bilinear + pack + single b64 write into the other buffer
    if (more) {
      const int c0n = (ch + 1) * KC;
      short4v pk;
      #pragma unroll
      for (int i = 0; i < 4; ++i) {
        const int kg = c0n + skc0 + i;
        const int c = kg / 9, tap = kg - c * 9;
        const float4 w4 = s_w[tap * PT + spx];
        const float v = w4.x * ga[i].x + w4.y * ga[i].y
                      + w4.z * gb[i].x + w4.w * gb[i].y;
        pk[i] = (short)f2bf(v);
      }
      const int byte = spx * 128 + ((skc0 * 2) ^ ((spx & 7) << 4));
      *(short4v*)((char*)s_col[cur ^ 1] + byte) = pk;
    }
    __syncthreads();
  }

  // ---- Epilogue: direct stores; C/D col(px)=lane&15, row(oc)=lg*4+r ----
  #pragma unroll
  for (int f = 0; f < 2; ++f) {
    const int oc = wv * 32 + f * 16 + lg * 4;
    #pragma unroll
    for (int j = 0; j < 2; ++j) {
      const int px = p0 + j * 16 + lm;
      #pragma unroll
      for (int r = 0; r < 4; ++r) {
        out[(size_t)(n * OCc + oc + r) * HW + px] = acc[f][j][r];
      }
    }
  }
}

extern "C" void kernel_launch(void* const* d_in, const int* in_sizes, int n_in,
                              void* d_out, int out_size, void* d_ws, size_t ws_size,
                              hipStream_t stream) {
  const float* x      = (const float*)d_in[0];
  const float* offset = (const float*)d_in[1];
  const float* weight = (const float*)d_in[2];
  float* out = (float*)d_out;
  unsigned short* wp = (unsigned short*)d_ws;

  pack_weight<<<dim3(NKB * 16 * 64 / 256), dim3(256), 0, stream>>>(weight, wp);
  dcn_mfma<<<dim3(HW / PT, 4), dim3(512), 0, stream>>>(x, offset, wp, out);
}

// Round 7
// 205.544 us; speedup vs baseline: 1.2083x; 1.2083x over previous
//
#include <hip/hip_runtime.h>

// Deformable conv2d (N=4, C=OC=256, 80x80, 3x3, s1 p1 d1):
// fused bilinear-im2col + bf16 MFMA GEMM, fp32 accumulate.
// R7: R3 structure (800 blocks x 4 waves, channel-inner k, 8-sample ILP,
//     b128 slab writes) + DEPTH-2 gather pipeline: triple-buffered LDS slab,
//     gathers for chunk ch+2 issued while MFMA(ch) runs and bilinear(ch+1)
//     finishes -> ~1 full chunk (~800+ cyc) of latency coverage per gather.

typedef short short8 __attribute__((ext_vector_type(8)));
typedef float floatx4 __attribute__((ext_vector_type(4)));
typedef float floatx2 __attribute__((ext_vector_type(2)));

#define Cc    256
#define OCc   256
#define Hh    80
#define Ww    80
#define HW    6400
#define KK    9
#define Ktot  2304
#define PT    32            // pixels per block
#define KC    64            // K per chunk
#define NCHUNK (Ktot / KC)  // 36
#define NKB   (Ktot / 32)   // 72

__device__ __forceinline__ unsigned short f2bf(float f) {
  unsigned u = __float_as_uint(f);
  u += 0x7FFF + ((u >> 16) & 1);
  return (unsigned short)(u >> 16);
}

// ---- Kernel 1: weight fp32 -> bf16 in MFMA A-fragment order ----
__global__ void pack_weight(const float* __restrict__ w,
                            unsigned short* __restrict__ wp) {
  const int t = blockIdx.x * 256 + threadIdx.x;   // 73728 threads
  const int lane = t & 63;
  const int ocf  = (t >> 6) & 15;
  const int kb   = t >> 10;
  const int oc   = ocf * 16 + (lane & 15);
  const int k0   = kb * 32 + (lane >> 4) * 8;
  const float* src = w + (size_t)oc * Ktot + k0;
  short8 pk;
  #pragma unroll
  for (int e = 0; e < 8; ++e) pk[e] = (short)f2bf(src[e]);
  *(short8*)(wp + (size_t)t * 8) = pk;
}

// ---- Kernel 2: fused sampling + MFMA, depth-2 pipeline ----
__global__ __launch_bounds__(256, 2) void dcn_mfma(
    const float* __restrict__ x, const float* __restrict__ offset,
    const unsigned short* __restrict__ wp, float* __restrict__ out) {
  __shared__ unsigned short s_col[3][PT * KC];  // 3 x 4KB, XOR-swizzled [px][k]
  __shared__ float4 s_w[KK * PT];               // corner weights (pre-swapped)
  __shared__ int2   s_i[KK * PT];               // paired-corner row bases

  const int tid  = threadIdx.x;
  const int lane = tid & 63;
  const int wv   = tid >> 6;
  const int n    = blockIdx.y;
  const int p0   = blockIdx.x * PT;

  // ---- Phase 0: bilinear coords; edge handling folded into weights ----
  for (int s = tid; s < KK * PT; s += 256) {
    const int k = s / PT, p = s % PT;
    const int pp = p0 + p;
    const int oy = pp / Ww, ox = pp % Ww;
    const int ky = k / 3, kx = k % 3;
    const float offy = offset[(size_t)(n * 18 + 2 * k    ) * HW + pp];
    const float offx = offset[(size_t)(n * 18 + 2 * k + 1) * HW + pp];
    const float py = offy + (float)(ky + oy - 1);
    const float px = offx + (float)(kx + ox - 1);
    const float fy0 = floorf(py), fx0 = floorf(px);
    const int iy0 = (int)fy0, ix0 = (int)fx0;
    const float wy1 = py - fy0, wx1 = px - fx0;
    const float wy0 = 1.f - wy1, wx0 = 1.f - wx1;
    const bool my0 = (iy0     >= 0) & (iy0     < Hh);
    const bool my1 = (iy0 + 1 >= 0) & (iy0 + 1 < Hh);
    const bool mx0 = (ix0     >= 0) & (ix0     < Ww);
    const bool mx1 = (ix0 + 1 >= 0) & (ix0 + 1 < Ww);
    const int cy0 = min(max(iy0,     0), Hh - 1);
    const int cy1 = min(max(iy0 + 1, 0), Hh - 1);
    const int bx  = min(max(ix0, 0), Ww - 2);   // dwordx2 base: [bx, bx+1]
    const bool sel = (ix0 == bx);
    const float wa = wx0 * wy0 * ((my0 && mx0) ? 1.f : 0.f);
    const float wb = wx1 * wy0 * ((my0 && mx1) ? 1.f : 0.f);
    const float wc = wx0 * wy1 * ((my1 && mx0) ? 1.f : 0.f);
    const float wd = wx1 * wy1 * ((my1 && mx1) ? 1.f : 0.f);
    float4 w4;  // pair-swap when x0 clamped off-base (masks make it exact)
    w4.x = sel ? wa : wb;  w4.y = sel ? wb : wa;
    w4.z = sel ? wc : wd;  w4.w = sel ? wd : wc;
    s_w[s] = w4;
    s_i[s] = make_int2(cy0 * Ww + bx, cy1 * Ww + bx);
  }

  floatx4 acc[4][2] = {};
  const int lm = lane & 15, lg = lane >> 4;
  const int spx  = tid & 31;        // sampling pixel
  const int skc0 = (tid >> 5) * 8;  // 8 consecutive k per thread
  __syncthreads();

  // issue chunk ch's 16 paired-corner gathers into registers
  auto issue = [&](int ch, floatx2* ga, floatx2* gb) {
    const int c0 = ch * KC;
    #pragma unroll
    for (int i = 0; i < 8; ++i) {
      const int kg = c0 + skc0 + i;
      const int c = kg / 9, tap = kg - c * 9;
      const int2 o2 = s_i[tap * PT + spx];
      const float* xp = x + (size_t)(n * Cc + c) * HW;
      ga[i] = *(const floatx2*)(xp + o2.x);
      gb[i] = *(const floatx2*)(xp + o2.y);
    }
  };
  // bilinear-combine + pack + single b128 write into buffer ch%3
  auto finish = [&](int ch, const floatx2* ga, const floatx2* gb) {
    const int c0 = ch * KC;
    short8 pk;
    #pragma unroll
    for (int i = 0; i < 8; ++i) {
      const int kg = c0 + skc0 + i;
      const int c = kg / 9, tap = kg - c * 9;
      const float4 w4 = s_w[tap * PT + spx];
      const float v = w4.x * ga[i].x + w4.y * ga[i].y
                    + w4.z * gb[i].x + w4.w * gb[i].y;
      pk[i] = (short)f2bf(v);
    }
    char* base = (char*)s_col + (ch % 3) * (PT * KC * 2);
    const int byte = spx * 128 + ((skc0 * 2) ^ ((spx & 7) << 4));
    *(short8*)(base + byte) = pk;
  };
  // 16 MFMAs on buffer ch%3
  auto mfma_step = [&](int ch) {
    const char* base = (const char*)s_col + (ch % 3) * (PT * KC * 2);
    const int kb0 = ch * 2;
    #pragma unroll
    for (int ks = 0; ks < 2; ++ks) {
      short8 b[2];
      #pragma unroll
      for (int j = 0; j < 2; ++j) {
        const int px = j * 16 + lm;
        const int byte = px * 128 + (((ks * 64) + lg * 16) ^ ((px & 7) << 4));
        b[j] = *(const short8*)(base + byte);
      }
      const size_t abase = (size_t)(kb0 + ks) * 16 * 64 * 8;
      #pragma unroll
      for (int f = 0; f < 4; ++f) {
        const int ocf = wv * 4 + f;
        const short8 a = *(const short8*)(wp + abase + (size_t)(ocf * 64 + lane) * 8);
        acc[f][0] = __builtin_amdgcn_mfma_f32_16x16x32_bf16(a, b[0], acc[f][0], 0, 0, 0);
        acc[f][1] = __builtin_amdgcn_mfma_f32_16x16x32_bf16(a, b[1], acc[f][1], 0, 0, 0);
      }
    }
  };

  floatx2 gaA[8], gbA[8], gaB[8], gbB[8];

  // ---- Prologue: fill buf0; leave A = gathers(1) in flight ----
  issue(0, gaA, gbA);
  finish(0, gaA, gbA);          // startup stall (once)
  issue(1, gaA, gbA);
  __syncthreads();

  // ---- Main: invariant at even ch: buf[ch%3] ready, A = gathers(ch+1) ----
  for (int it = 0; it < NCHUNK / 2; ++it) {
    const int ch = it * 2;
    // even sub-iter: scratch = B
    if (ch + 2 < NCHUNK) issue(ch + 2, gaB, gbB);
    mfma_step(ch);
    finish(ch + 1, gaA, gbA);   // issued a full chunk ago -> latency hidden
    __syncthreads();
    // odd sub-iter: scratch = A
    if (ch + 3 < NCHUNK) issue(ch + 3, gaA, gbA);
    mfma_step(ch + 1);
    if (ch + 2 < NCHUNK) finish(ch + 2, gaB, gbB);
    __syncthreads();
  }

  // ---- Epilogue: direct stores; C/D col(px)=lane&15, row(oc)=lg*4+r ----
  #pragma unroll
  for (int f = 0; f < 4; ++f) {
    const int oc = wv * 64 + f * 16 + lg * 4;
    #pragma unroll
    for (int j = 0; j < 2; ++j) {
      const int px = p0 + j * 16 + lm;
      #pragma unroll
      for (int r = 0; r < 4; ++r) {
        out[(size_t)(n * OCc + oc + r) * HW + px] = acc[f][j][r];
      }
    }
  }
}

extern "C" void kernel_launch(void* const* d_in, const int* in_sizes, int n_in,
                              void* d_out, int out_size, void* d_ws, size_t ws_size,
                              hipStream_t stream) {
  const float* x      = (const float*)d_in[0];
  const float* offset = (const float*)d_in[1];
  const float* weight = (const float*)d_in[2];
  float* out = (float*)d_out;
  unsigned short* wp = (unsigned short*)d_ws;

  pack_weight<<<dim3(NKB * 16 * 64 / 256), dim3(256), 0, stream>>>(weight, wp);
  dcn_mfma<<<dim3(HW / PT, 4), dim3(256), 0, stream>>>(x, offset, wp, out);
}

// Round 8
// 128.219 us; speedup vs baseline: 1.9370x; 1.6031x over previous
//
#include <hip/hip_runtime.h>

// Deformable conv2d (N=4, C=OC=256, 80x80, 3x3, s1 p1 d1):
// fused bilinear-im2col + bf16 MFMA GEMM, fp32 accumulate.
// R8: NHWC-bf16 staging of x in d_ws -> channel-inner gathers. Each
//     (px,tap,corner) sample-read is a dense 16B dwordx4 of 8 channels:
//     ~3.8x fewer L1 lines than NCHW scatter (the R3 limiter). K is
//     tap-major (k'=tap*256+c); weight pack matches. R3's double-buffered
//     slab pipeline and verified XOR-swizzle retained.

typedef short short8 __attribute__((ext_vector_type(8)));
typedef float floatx4 __attribute__((ext_vector_type(4)));

#define Cc    256
#define OCc   256
#define Hh    80
#define Ww    80
#define HW    6400
#define KK    9
#define Ktot  2304
#define PT    32            // pixels per block
#define KC    64            // K per chunk = one tap x 64 channels
#define NCHUNK (Ktot / KC)  // 36
#define NKB   (Ktot / 32)   // 72
#define WP_ELEMS (Ktot * OCc)          // 589824 ushorts (1.18 MB)
#define XT_OFF   ((size_t)WP_ELEMS)    // xt starts right after wp in d_ws

__device__ __forceinline__ unsigned short f2bf(float f) {
  unsigned u = __float_as_uint(f);
  u += 0x7FFF + ((u >> 16) & 1);
  return (unsigned short)(u >> 16);
}
__device__ __forceinline__ float bf2f(unsigned short u) {
  return __uint_as_float((unsigned)u << 16);
}

// ---- Kernel 1: weight fp32 -> bf16 A-fragments, tap-major K (k'=tap*256+c) --
__global__ void pack_weight(const float* __restrict__ w,
                            unsigned short* __restrict__ wp) {
  const int t = blockIdx.x * 256 + threadIdx.x;   // 73728 threads
  const int lane = t & 63;
  const int ocf  = (t >> 6) & 15;
  const int kb   = t >> 10;
  const int oc   = ocf * 16 + (lane & 15);
  const int k0   = kb * 32 + (lane >> 4) * 8;     // 8 consecutive k'
  const int tap  = k0 >> 8;                       // constant across the 8
  const int c0   = k0 & 255;
  const float* src = w + (size_t)oc * Ktot + (size_t)c0 * KK + tap;
  short8 pk;
  #pragma unroll
  for (int e = 0; e < 8; ++e) pk[e] = (short)f2bf(src[e * KK]);
  *(short8*)(wp + (size_t)t * 8) = pk;
}

// ---- Kernel 2: x NCHW fp32 -> NHWC bf16 (xt[n][hw][c]) ----
__global__ void nhwc_pack(const float* __restrict__ x,
                          unsigned short* __restrict__ xt) {
  __shared__ float tile[64][65];
  const int tid = threadIdx.x;
  const int hw0 = blockIdx.x * 64;
  const int c0  = blockIdx.y * 64;
  const int n   = blockIdx.z;
  #pragma unroll
  for (int i = 0; i < 16; ++i) {
    const int idx = i * 256 + tid;
    const int cl = idx >> 6, hl = idx & 63;
    tile[cl][hl] = x[((size_t)(n * Cc + c0 + cl)) * HW + hw0 + hl];  // coalesced
  }
  __syncthreads();
  #pragma unroll
  for (int i = 0; i < 16; ++i) {
    const int idx = i * 256 + tid;
    const int hl = idx >> 6, cl = idx & 63;
    xt[((size_t)(n * HW + hw0 + hl)) * Cc + c0 + cl] = f2bf(tile[cl][hl]);
  }
}

// ---- Kernel 3: fused sampling + MFMA ----
__global__ __launch_bounds__(256, 3) void dcn_mfma(
    const float* __restrict__ x, const float* __restrict__ offset,
    const unsigned short* __restrict__ wp,
    const unsigned short* __restrict__ xt, float* __restrict__ out) {
  __shared__ unsigned short s_col[2][PT * KC];  // 2 x 4KB, XOR-swizzled [px][k]
  __shared__ float4 s_w[KK * PT];               // masked corner weights
  __shared__ int4   s_i[KK * PT];               // corner byte offsets (hw*512)

  const int tid  = threadIdx.x;
  const int lane = tid & 63;
  const int wv   = tid >> 6;
  const int n    = blockIdx.y;
  const int p0   = blockIdx.x * PT;
  const char* xn = (const char*)(xt + (size_t)n * HW * Cc);

  // ---- Phase 0: bilinear coords; masks folded into per-corner weights ----
  for (int s = tid; s < KK * PT; s += 256) {
    const int k = s / PT, p = s % PT;
    const int pp = p0 + p;
    const int oy = pp / Ww, ox = pp % Ww;
    const int ky = k / 3, kx = k % 3;
    const float offy = offset[(size_t)(n * 18 + 2 * k    ) * HW + pp];
    const float offx = offset[(size_t)(n * 18 + 2 * k + 1) * HW + pp];
    const float py = offy + (float)(ky + oy - 1);
    const float px = offx + (float)(kx + ox - 1);
    const float fy0 = floorf(py), fx0 = floorf(px);
    const int iy0 = (int)fy0, ix0 = (int)fx0;
    const float wy1 = py - fy0, wx1 = px - fx0;
    const float wy0 = 1.f - wy1, wx0 = 1.f - wx1;
    const bool my0 = (iy0     >= 0) & (iy0     < Hh);
    const bool my1 = (iy0 + 1 >= 0) & (iy0 + 1 < Hh);
    const bool mx0 = (ix0     >= 0) & (ix0     < Ww);
    const bool mx1 = (ix0 + 1 >= 0) & (ix0 + 1 < Ww);
    const int cy0 = min(max(iy0,     0), Hh - 1);
    const int cy1 = min(max(iy0 + 1, 0), Hh - 1);
    const int cx0 = min(max(ix0,     0), Ww - 1);
    const int cx1 = min(max(ix0 + 1, 0), Ww - 1);
    float4 w4;
    w4.x = wx0 * wy0 * ((my0 && mx0) ? 1.f : 0.f);
    w4.y = wx1 * wy0 * ((my0 && mx1) ? 1.f : 0.f);
    w4.z = wx0 * wy1 * ((my1 && mx0) ? 1.f : 0.f);
    w4.w = wx1 * wy1 * ((my1 && mx1) ? 1.f : 0.f);
    int4 i4;  // byte offsets into xt[n]: hw * 256ch * 2B
    i4.x = (cy0 * Ww + cx0) * 512;  i4.y = (cy0 * Ww + cx1) * 512;
    i4.z = (cy1 * Ww + cx0) * 512;  i4.w = (cy1 * Ww + cx1) * 512;
    s_w[s] = w4;
    s_i[s] = i4;
  }

  floatx4 acc[4][2] = {};
  const int lm = lane & 15, lg = lane >> 4;
  const int spx = tid & 31;         // sampling pixel
  const int cg  = tid >> 5;         // channel group: 8 channels
  const int wbyte = spx * 128 + ((cg * 16) ^ ((spx & 7) << 4));  // slab write
  __syncthreads();

  short8 ra, rb, rc, rd;            // 4 corner loads in flight (16 VGPR)

  // issue chunk ch's 4 dense corner loads (8 channels each)
  auto issue = [&](int ch) {
    const int tap = ch >> 2;
    const int coff = ((ch & 3) * KC + cg * 8) * 2;   // channel byte offset
    const int4 i4 = s_i[tap * PT + spx];
    ra = *(const short8*)(xn + i4.x + coff);
    rb = *(const short8*)(xn + i4.y + coff);
    rc = *(const short8*)(xn + i4.z + coff);
    rd = *(const short8*)(xn + i4.w + coff);
  };
  // bilinear combine 8 channels + pack + single b128 slab write
  auto finish = [&](int ch, int buf) {
    const int tap = ch >> 2;
    const float4 w4 = s_w[tap * PT + spx];
    short8 pk;
    #pragma unroll
    for (int e = 0; e < 8; ++e) {
      const float v = w4.x * bf2f((unsigned short)ra[e])
                    + w4.y * bf2f((unsigned short)rb[e])
                    + w4.z * bf2f((unsigned short)rc[e])
                    + w4.w * bf2f((unsigned short)rd[e]);
      pk[e] = (short)f2bf(v);
    }
    *(short8*)((char*)s_col[buf] + wbyte) = pk;
  };

  // ---- Prologue ----
  issue(0);
  finish(0, 0);
  __syncthreads();

  // ---- Main pipeline over 36 chunks ----
  for (int ch = 0; ch < NCHUNK; ++ch) {
    const int cur = ch & 1;
    const bool more = (ch + 1 < NCHUNK);

    if (more) issue(ch + 1);        // gathers hide under MFMA + A-loads

    const int kb0 = ch * 2;
    #pragma unroll
    for (int ks = 0; ks < 2; ++ks) {
      short8 b[2];
      #pragma unroll
      for (int j = 0; j < 2; ++j) {
        const int px = j * 16 + lm;
        const int byte = px * 128 + (((ks * 64) + lg * 16) ^ ((px & 7) << 4));
        b[j] = *(const short8*)((const char*)s_col[cur] + byte);
      }
      const size_t abase = (size_t)(kb0 + ks) * 16 * 64 * 8;
      #pragma unroll
      for (int f = 0; f < 4; ++f) {
        const int ocf = wv * 4 + f;
        const short8 a = *(const short8*)(wp + abase + (size_t)(ocf * 64 + lane) * 8);
        acc[f][0] = __builtin_amdgcn_mfma_f32_16x16x32_bf16(a, b[0], acc[f][0], 0, 0, 0);
        acc[f][1] = __builtin_amdgcn_mfma_f32_16x16x32_bf16(a, b[1], acc[f][1], 0, 0, 0);
      }
    }

    if (more) finish(ch + 1, cur ^ 1);
    __syncthreads();
  }

  // ---- Epilogue: direct stores; C/D col(px)=lane&15, row(oc)=lg*4+r ----
  #pragma unroll
  for (int f = 0; f < 4; ++f) {
    const int oc = wv * 64 + f * 16 + lg * 4;
    #pragma unroll
    for (int j = 0; j < 2; ++j) {
      const int px = p0 + j * 16 + lm;
      #pragma unroll
      for (int r = 0; r < 4; ++r) {
        out[(size_t)(n * OCc + oc + r) * HW + px] = acc[f][j][r];
      }
    }
  }
}

extern "C" void kernel_launch(void* const* d_in, const int* in_sizes, int n_in,
                              void* d_out, int out_size, void* d_ws, size_t ws_size,
                              hipStream_t stream) {
  const float* x      = (const float*)d_in[0];
  const float* offset = (const float*)d_in[1];
  const float* weight = (const float*)d_in[2];
  float* out = (float*)d_out;
  unsigned short* wp = (unsigned short*)d_ws;              // 1.18 MB
  unsigned short* xt = (unsigned short*)d_ws + XT_OFF;     // 13.1 MB

  pack_weight<<<dim3(NKB * 16 * 64 / 256), dim3(256), 0, stream>>>(weight, wp);
  nhwc_pack<<<dim3(HW / 64, Cc / 64, 4), dim3(256), 0, stream>>>(x, xt);
  dcn_mfma<<<dim3(HW / PT, 4), dim3(256), 0, stream>>>(x, offset, wp, xt, out);
}

// Round 9
// 125.640 us; speedup vs baseline: 1.9767x; 1.0205x over previous
//
#include <hip/hip_runtime.h>

// Deformable conv2d (N=4, C=OC=256, 80x80, 3x3, s1 p1 d1):
// fused bilinear-im2col + bf16 MFMA GEMM, fp32 accumulate.
// R9 = R8 (NHWC-bf16 xt staging, tap-major K, dense 16B channel-gathers)
//  + XCD-aware bijective block swizzle: each XCD gets 100 contiguous pixel
//    tiles -> per-XCD L2 working set ~2.9MB < 4MB (was ~14MB -> L3 latency)
//  + depth-2 gather pipeline with two named 16-VGPR register sets and a
//    triple-buffered slab (R7's scheme; R7 failed on 64-VGPR state, ours is 32).

typedef short short8 __attribute__((ext_vector_type(8)));
typedef float floatx4 __attribute__((ext_vector_type(4)));

#define Cc    256
#define OCc   256
#define Hh    80
#define Ww    80
#define HW    6400
#define KK    9
#define Ktot  2304
#define PT    32            // pixels per block
#define KC    64            // K per chunk = one tap x 64 channels
#define NCHUNK (Ktot / KC)  // 36
#define NKB   (Ktot / 32)   // 72
#define WP_ELEMS (Ktot * OCc)          // 589824 ushorts (1.18 MB)
#define XT_OFF   ((size_t)WP_ELEMS)

__device__ __forceinline__ unsigned short f2bf(float f) {
  unsigned u = __float_as_uint(f);
  u += 0x7FFF + ((u >> 16) & 1);
  return (unsigned short)(u >> 16);
}
__device__ __forceinline__ float bf2f(unsigned short u) {
  return __uint_as_float((unsigned)u << 16);
}

// ---- Kernel 1: weight fp32 -> bf16 A-fragments, tap-major K (k'=tap*256+c) --
__global__ void pack_weight(const float* __restrict__ w,
                            unsigned short* __restrict__ wp) {
  const int t = blockIdx.x * 256 + threadIdx.x;   // 73728 threads
  const int lane = t & 63;
  const int ocf  = (t >> 6) & 15;
  const int kb   = t >> 10;
  const int oc   = ocf * 16 + (lane & 15);
  const int k0   = kb * 32 + (lane >> 4) * 8;     // 8 consecutive k'
  const int tap  = k0 >> 8;
  const int c0   = k0 & 255;
  const float* src = w + (size_t)oc * Ktot + (size_t)c0 * KK + tap;
  short8 pk;
  #pragma unroll
  for (int e = 0; e < 8; ++e) pk[e] = (short)f2bf(src[e * KK]);
  *(short8*)(wp + (size_t)t * 8) = pk;
}

// ---- Kernel 2: x NCHW fp32 -> NHWC bf16 (xt[n][hw][c]) ----
__global__ void nhwc_pack(const float* __restrict__ x,
                          unsigned short* __restrict__ xt) {
  __shared__ float tile[64][65];
  const int tid = threadIdx.x;
  const int hw0 = blockIdx.x * 64;
  const int c0  = blockIdx.y * 64;
  const int n   = blockIdx.z;
  #pragma unroll
  for (int i = 0; i < 16; ++i) {
    const int idx = i * 256 + tid;
    const int cl = idx >> 6, hl = idx & 63;
    tile[cl][hl] = x[((size_t)(n * Cc + c0 + cl)) * HW + hw0 + hl];
  }
  __syncthreads();
  #pragma unroll
  for (int i = 0; i < 16; ++i) {
    const int idx = i * 256 + tid;
    const int hl = idx >> 6, cl = idx & 63;
    xt[((size_t)(n * HW + hw0 + hl)) * Cc + c0 + cl] = f2bf(tile[cl][hl]);
  }
}

// ---- Kernel 3: fused sampling + MFMA ----
__global__ __launch_bounds__(256, 3) void dcn_mfma(
    const float* __restrict__ x, const float* __restrict__ offset,
    const unsigned short* __restrict__ wp,
    const unsigned short* __restrict__ xt, float* __restrict__ out) {
  __shared__ unsigned short s_col[3][PT * KC];  // 3 x 4KB, XOR-swizzled [px][k]
  __shared__ float4 s_w[KK * PT];               // masked corner weights
  __shared__ int4   s_i[KK * PT];               // corner byte offsets (hw*512)

  const int tid  = threadIdx.x;
  const int lane = tid & 63;
  const int wv   = tid >> 6;

  // XCD-aware bijective swizzle: 800 blocks = 8 XCDs x 100 contiguous tiles
  const int bid  = blockIdx.x;
  const int logical = (bid & 7) * 100 + (bid >> 3);
  const int n    = logical / (HW / PT / 4 * 4) >= 4 ? 3 : logical / 200; // guard
  const int nn   = logical / 200;
  const int tile = logical - nn * 200;
  const int p0   = tile * PT;
  (void)n;
  const char* xn = (const char*)(xt + (size_t)nn * HW * Cc);

  // ---- Phase 0: bilinear coords; masks folded into per-corner weights ----
  for (int s = tid; s < KK * PT; s += 256) {
    const int k = s / PT, p = s % PT;
    const int pp = p0 + p;
    const int oy = pp / Ww, ox = pp % Ww;
    const int ky = k / 3, kx = k % 3;
    const float offy = offset[(size_t)(nn * 18 + 2 * k    ) * HW + pp];
    const float offx = offset[(size_t)(nn * 18 + 2 * k + 1) * HW + pp];
    const float py = offy + (float)(ky + oy - 1);
    const float px = offx + (float)(kx + ox - 1);
    const float fy0 = floorf(py), fx0 = floorf(px);
    const int iy0 = (int)fy0, ix0 = (int)fx0;
    const float wy1 = py - fy0, wx1 = px - fx0;
    const float wy0 = 1.f - wy1, wx0 = 1.f - wx1;
    const bool my0 = (iy0     >= 0) & (iy0     < Hh);
    const bool my1 = (iy0 + 1 >= 0) & (iy0 + 1 < Hh);
    const bool mx0 = (ix0     >= 0) & (ix0     < Ww);
    const bool mx1 = (ix0 + 1 >= 0) & (ix0 + 1 < Ww);
    const int cy0 = min(max(iy0,     0), Hh - 1);
    const int cy1 = min(max(iy0 + 1, 0), Hh - 1);
    const int cx0 = min(max(ix0,     0), Ww - 1);
    const int cx1 = min(max(ix0 + 1, 0), Ww - 1);
    float4 w4;
    w4.x = wx0 * wy0 * ((my0 && mx0) ? 1.f : 0.f);
    w4.y = wx1 * wy0 * ((my0 && mx1) ? 1.f : 0.f);
    w4.z = wx0 * wy1 * ((my1 && mx0) ? 1.f : 0.f);
    w4.w = wx1 * wy1 * ((my1 && mx1) ? 1.f : 0.f);
    int4 i4;  // byte offsets into xt[n]: hw * 256ch * 2B
    i4.x = (cy0 * Ww + cx0) * 512;  i4.y = (cy0 * Ww + cx1) * 512;
    i4.z = (cy1 * Ww + cx0) * 512;  i4.w = (cy1 * Ww + cx1) * 512;
    s_w[s] = w4;
    s_i[s] = i4;
  }

  floatx4 acc[4][2] = {};
  const int lm = lane & 15, lg = lane >> 4;
  const int spx = tid & 31;         // sampling pixel
  const int cg  = tid >> 5;         // channel group: 8 channels
  const int wbyte = spx * 128 + ((cg * 16) ^ ((spx & 7) << 4));
  __syncthreads();

  // Two named in-flight gather sets (16 VGPR each) — rule #20: static names.
  short8 raA, rbA, rcA, rdA, raB, rbB, rcB, rdB;

  #define ISSUE(ch, S)                                                  \
    { const int tap_ = (ch) >> 2;                                       \
      const int coff_ = (((ch) & 3) * KC + cg * 8) * 2;                 \
      const int4 i4_ = s_i[tap_ * PT + spx];                            \
      ra##S = *(const short8*)(xn + i4_.x + coff_);                     \
      rb##S = *(const short8*)(xn + i4_.y + coff_);                     \
      rc##S = *(const short8*)(xn + i4_.z + coff_);                     \
      rd##S = *(const short8*)(xn + i4_.w + coff_); }

  #define FINISH(ch, S)                                                 \
    { const int tap_ = (ch) >> 2;                                       \
      const float4 w4_ = s_w[tap_ * PT + spx];                          \
      short8 pk_;                                                       \
      _Pragma("unroll")                                                 \
      for (int e = 0; e < 8; ++e) {                                     \
        const float v_ = w4_.x * bf2f((unsigned short)ra##S[e])         \
                       + w4_.y * bf2f((unsigned short)rb##S[e])         \
                       + w4_.z * bf2f((unsigned short)rc##S[e])         \
                       + w4_.w * bf2f((unsigned short)rd##S[e]);        \
        pk_[e] = (short)f2bf(v_);                                       \
      }                                                                 \
      *(short8*)((char*)s_col[(ch) % 3] + wbyte) = pk_; }

  auto mfma_step = [&](int ch) {
    const char* base = (const char*)s_col[ch % 3];
    const int kb0 = ch * 2;
    #pragma unroll
    for (int ks = 0; ks < 2; ++ks) {
      short8 b[2];
      #pragma unroll
      for (int j = 0; j < 2; ++j) {
        const int px = j * 16 + lm;
        const int byte = px * 128 + (((ks * 64) + lg * 16) ^ ((px & 7) << 4));
        b[j] = *(const short8*)(base + byte);
      }
      const size_t abase = (size_t)(kb0 + ks) * 16 * 64 * 8;
      #pragma unroll
      for (int f = 0; f < 4; ++f) {
        const int ocf = wv * 4 + f;
        const short8 a = *(const short8*)(wp + abase + (size_t)(ocf * 64 + lane) * 8);
        acc[f][0] = __builtin_amdgcn_mfma_f32_16x16x32_bf16(a, b[0], acc[f][0], 0, 0, 0);
        acc[f][1] = __builtin_amdgcn_mfma_f32_16x16x32_bf16(a, b[1], acc[f][1], 0, 0, 0);
      }
    }
  };

  // ---- Prologue: buf0 ready; A = gathers(1) in flight ----
  ISSUE(0, A);
  FINISH(0, A);          // startup stall (once)
  ISSUE(1, A);
  __syncthreads();

  // ---- Main: at even ch, invariant: buf[ch%3] ready, A holds ch+1 ----
  for (int it = 0; it < NCHUNK / 2; ++it) {
    const int ch = it * 2;
    if (ch + 2 < NCHUNK) ISSUE(ch + 2, B);
    mfma_step(ch);
    FINISH(ch + 1, A);   // loads issued a full chunk (2 barriers) ago
    __syncthreads();
    if (ch + 3 < NCHUNK) ISSUE(ch + 3, A);
    mfma_step(ch + 1);
    if (ch + 2 < NCHUNK) FINISH(ch + 2, B);
    __syncthreads();
  }

  // ---- Epilogue: direct stores; C/D col(px)=lane&15, row(oc)=lg*4+r ----
  #pragma unroll
  for (int f = 0; f < 4; ++f) {
    const int oc = wv * 64 + f * 16 + lg * 4;
    #pragma unroll
    for (int j = 0; j < 2; ++j) {
      const int px = p0 + j * 16 + lm;
      #pragma unroll
      for (int r = 0; r < 4; ++r) {
        out[(size_t)(nn * OCc + oc + r) * HW + px] = acc[f][j][r];
      }
    }
  }
}

extern "C" void kernel_launch(void* const* d_in, const int* in_sizes, int n_in,
                              void* d_out, int out_size, void* d_ws, size_t ws_size,
                              hipStream_t stream) {
  const float* x      = (const float*)d_in[0];
  const float* offset = (const float*)d_in[1];
  const float* weight = (const float*)d_in[2];
  float* out = (float*)d_out;
  unsigned short* wp = (unsigned short*)d_ws;              // 1.18 MB
  unsigned short* xt = (unsigned short*)d_ws + XT_OFF;     // 13.1 MB

  pack_weight<<<dim3(NKB * 16 * 64 / 256), dim3(256), 0, stream>>>(weight, wp);
  nhwc_pack<<<dim3(HW / 64, Cc / 64, 4), dim3(256), 0, stream>>>(x, xt);
  dcn_mfma<<<dim3(800), dim3(256), 0, stream>>>(x, offset, wp, xt, out);
}

// Round 10
// 122.712 us; speedup vs baseline: 2.0239x; 1.0239x over previous
//
#include <hip/hip_runtime.h>

// Deformable conv2d (N=4, C=OC=256, 80x80, 3x3, s1 p1 d1):
// fused bilinear-im2col + bf16 MFMA GEMM, fp32 accumulate.
// R10 = R9 (NHWC-bf16 xt, tap-major K, XCD swizzle, depth-2 reg pipeline,
//      triple-buffered slab) with ONE change: per-chunk __syncthreads()
//      [which compiles to s_waitcnt vmcnt(0) lgkmcnt(0); s_barrier -- draining
//      the prefetch gathers every chunk, m97 mechanism] replaced by
//      lgkmcnt(0)-only + raw s_barrier. In-flight vmem gathers now survive
//      across barriers; compiler's per-use counted vmcnt covers RAW on regs.

typedef short short8 __attribute__((ext_vector_type(8)));
typedef float floatx4 __attribute__((ext_vector_type(4)));

#define Cc    256
#define OCc   256
#define Hh    80
#define Ww    80
#define HW    6400
#define KK    9
#define Ktot  2304
#define PT    32            // pixels per block
#define KC    64            // K per chunk = one tap x 64 channels
#define NCHUNK (Ktot / KC)  // 36
#define NKB   (Ktot / 32)   // 72
#define WP_ELEMS (Ktot * OCc)          // 589824 ushorts (1.18 MB)
#define XT_OFF   ((size_t)WP_ELEMS)

// Relaxed barrier: retire LDS ops, but let vmem gathers stay in flight.
#define BARRIER_LDS()                                      \
  do {                                                     \
    asm volatile("s_waitcnt lgkmcnt(0)" ::: "memory");     \
    __builtin_amdgcn_s_barrier();                          \
  } while (0)

__device__ __forceinline__ unsigned short f2bf(float f) {
  unsigned u = __float_as_uint(f);
  u += 0x7FFF + ((u >> 16) & 1);
  return (unsigned short)(u >> 16);
}
__device__ __forceinline__ float bf2f(unsigned short u) {
  return __uint_as_float((unsigned)u << 16);
}

// ---- Kernel 1: weight fp32 -> bf16 A-fragments, tap-major K (k'=tap*256+c) --
__global__ void pack_weight(const float* __restrict__ w,
                            unsigned short* __restrict__ wp) {
  const int t = blockIdx.x * 256 + threadIdx.x;   // 73728 threads
  const int lane = t & 63;
  const int ocf  = (t >> 6) & 15;
  const int kb   = t >> 10;
  const int oc   = ocf * 16 + (lane & 15);
  const int k0   = kb * 32 + (lane >> 4) * 8;     // 8 consecutive k'
  const int tap  = k0 >> 8;
  const int c0   = k0 & 255;
  const float* src = w + (size_t)oc * Ktot + (size_t)c0 * KK + tap;
  short8 pk;
  #pragma unroll
  for (int e = 0; e < 8; ++e) pk[e] = (short)f2bf(src[e * KK]);
  *(short8*)(wp + (size_t)t * 8) = pk;
}

// ---- Kernel 2: x NCHW fp32 -> NHWC bf16 (xt[n][hw][c]) ----
__global__ void nhwc_pack(const float* __restrict__ x,
                          unsigned short* __restrict__ xt) {
  __shared__ float tile[64][65];
  const int tid = threadIdx.x;
  const int hw0 = blockIdx.x * 64;
  const int c0  = blockIdx.y * 64;
  const int n   = blockIdx.z;
  #pragma unroll
  for (int i = 0; i < 16; ++i) {
    const int idx = i * 256 + tid;
    const int cl = idx >> 6, hl = idx & 63;
    tile[cl][hl] = x[((size_t)(n * Cc + c0 + cl)) * HW + hw0 + hl];
  }
  __syncthreads();
  #pragma unroll
  for (int i = 0; i < 16; ++i) {
    const int idx = i * 256 + tid;
    const int hl = idx >> 6, cl = idx & 63;
    xt[((size_t)(n * HW + hw0 + hl)) * Cc + c0 + cl] = f2bf(tile[cl][hl]);
  }
}

// ---- Kernel 3: fused sampling + MFMA ----
__global__ __launch_bounds__(256, 3) void dcn_mfma(
    const float* __restrict__ x, const float* __restrict__ offset,
    const unsigned short* __restrict__ wp,
    const unsigned short* __restrict__ xt, float* __restrict__ out) {
  __shared__ unsigned short s_col[3][PT * KC];  // 3 x 4KB, XOR-swizzled [px][k]
  __shared__ float4 s_w[KK * PT];               // masked corner weights
  __shared__ int4   s_i[KK * PT];               // corner byte offsets (hw*512)

  const int tid  = threadIdx.x;
  const int lane = tid & 63;
  const int wv   = tid >> 6;

  // XCD-aware bijective swizzle: 800 blocks = 8 XCDs x 100 contiguous tiles
  const int bid  = blockIdx.x;
  const int logical = (bid & 7) * 100 + (bid >> 3);
  const int nn   = logical / 200;
  const int tile = logical - nn * 200;
  const int p0   = tile * PT;
  const char* xn = (const char*)(xt + (size_t)nn * HW * Cc);

  // ---- Phase 0: bilinear coords; masks folded into per-corner weights ----
  for (int s = tid; s < KK * PT; s += 256) {
    const int k = s / PT, p = s % PT;
    const int pp = p0 + p;
    const int oy = pp / Ww, ox = pp % Ww;
    const int ky = k / 3, kx = k % 3;
    const float offy = offset[(size_t)(nn * 18 + 2 * k    ) * HW + pp];
    const float offx = offset[(size_t)(nn * 18 + 2 * k + 1) * HW + pp];
    const float py = offy + (float)(ky + oy - 1);
    const float px = offx + (float)(kx + ox - 1);
    const float fy0 = floorf(py), fx0 = floorf(px);
    const int iy0 = (int)fy0, ix0 = (int)fx0;
    const float wy1 = py - fy0, wx1 = px - fx0;
    const float wy0 = 1.f - wy1, wx0 = 1.f - wx1;
    const bool my0 = (iy0     >= 0) & (iy0     < Hh);
    const bool my1 = (iy0 + 1 >= 0) & (iy0 + 1 < Hh);
    const bool mx0 = (ix0     >= 0) & (ix0     < Ww);
    const bool mx1 = (ix0 + 1 >= 0) & (ix0 + 1 < Ww);
    const int cy0 = min(max(iy0,     0), Hh - 1);
    const int cy1 = min(max(iy0 + 1, 0), Hh - 1);
    const int cx0 = min(max(ix0,     0), Ww - 1);
    const int cx1 = min(max(ix0 + 1, 0), Ww - 1);
    float4 w4;
    w4.x = wx0 * wy0 * ((my0 && mx0) ? 1.f : 0.f);
    w4.y = wx1 * wy0 * ((my0 && mx1) ? 1.f : 0.f);
    w4.z = wx0 * wy1 * ((my1 && mx0) ? 1.f : 0.f);
    w4.w = wx1 * wy1 * ((my1 && mx1) ? 1.f : 0.f);
    int4 i4;  // byte offsets into xt[n]: hw * 256ch * 2B
    i4.x = (cy0 * Ww + cx0) * 512;  i4.y = (cy0 * Ww + cx1) * 512;
    i4.z = (cy1 * Ww + cx0) * 512;  i4.w = (cy1 * Ww + cx1) * 512;
    s_w[s] = w4;
    s_i[s] = i4;
  }

  floatx4 acc[4][2] = {};
  const int lm = lane & 15, lg = lane >> 4;
  const int spx = tid & 31;         // sampling pixel
  const int cg  = tid >> 5;         // channel group: 8 channels
  const int wbyte = spx * 128 + ((cg * 16) ^ ((spx & 7) << 4));
  __syncthreads();                  // once; full drain here is fine

  // Two named in-flight gather sets (16 VGPR each) — rule #20: static names.
  short8 raA, rbA, rcA, rdA, raB, rbB, rcB, rdB;

  #define ISSUE(ch, S)                                                  \
    { const int tap_ = (ch) >> 2;                                       \
      const int coff_ = (((ch) & 3) * KC + cg * 8) * 2;                 \
      const int4 i4_ = s_i[tap_ * PT + spx];                            \
      ra##S = *(const short8*)(xn + i4_.x + coff_);                     \
      rb##S = *(const short8*)(xn + i4_.y + coff_);                     \
      rc##S = *(const short8*)(xn + i4_.z + coff_);                     \
      rd##S = *(const short8*)(xn + i4_.w + coff_); }

  #define FINISH(ch, S)                                                 \
    { const int tap_ = (ch) >> 2;                                       \
      const float4 w4_ = s_w[tap_ * PT + spx];                          \
      short8 pk_;                                                       \
      _Pragma("unroll")                                                 \
      for (int e = 0; e < 8; ++e) {                                     \
        const float v_ = w4_.x * bf2f((unsigned short)ra##S[e])         \
                       + w4_.y * bf2f((unsigned short)rb##S[e])         \
                       + w4_.z * bf2f((unsigned short)rc##S[e])         \
                       + w4_.w * bf2f((unsigned short)rd##S[e]);        \
        pk_[e] = (short)f2bf(v_);                                       \
      }                                                                 \
      *(short8*)((char*)s_col[(ch) % 3] + wbyte) = pk_; }

  auto mfma_step = [&](int ch) {
    const char* base = (const char*)s_col[ch % 3];
    const int kb0 = ch * 2;
    #pragma unroll
    for (int ks = 0; ks < 2; ++ks) {
      short8 b[2];
      #pragma unroll
      for (int j = 0; j < 2; ++j) {
        const int px = j * 16 + lm;
        const int byte = px * 128 + (((ks * 64) + lg * 16) ^ ((px & 7) << 4));
        b[j] = *(const short8*)(base + byte);
      }
      const size_t abase = (size_t)(kb0 + ks) * 16 * 64 * 8;
      #pragma unroll
      for (int f = 0; f < 4; ++f) {
        const int ocf = wv * 4 + f;
        const short8 a = *(const short8*)(wp + abase + (size_t)(ocf * 64 + lane) * 8);
        acc[f][0] = __builtin_amdgcn_mfma_f32_16x16x32_bf16(a, b[0], acc[f][0], 0, 0, 0);
        acc[f][1] = __builtin_amdgcn_mfma_f32_16x16x32_bf16(a, b[1], acc[f][1], 0, 0, 0);
      }
    }
  };

  // ---- Prologue: buf0 ready; A = gathers(1) in flight ----
  ISSUE(0, A);
  FINISH(0, A);          // startup stall (once)
  ISSUE(1, A);
  BARRIER_LDS();

  // ---- Main: at even ch, invariant: buf[ch%3] ready, A holds ch+1 ----
  for (int it = 0; it < NCHUNK / 2; ++it) {
    const int ch = it * 2;
    if (ch + 2 < NCHUNK) ISSUE(ch + 2, B);
    mfma_step(ch);
    FINISH(ch + 1, A);   // loads issued a full iteration ago; counted vmcnt
    BARRIER_LDS();
    if (ch + 3 < NCHUNK) ISSUE(ch + 3, A);
    mfma_step(ch + 1);
    if (ch + 2 < NCHUNK) FINISH(ch + 2, B);
    BARRIER_LDS();
  }

  // ---- Epilogue: direct stores; C/D col(px)=lane&15, row(oc)=lg*4+r ----
  #pragma unroll
  for (int f = 0; f < 4; ++f) {
    const int oc = wv * 64 + f * 16 + lg * 4;
    #pragma unroll
    for (int j = 0; j < 2; ++j) {
      const int px = p0 + j * 16 + lm;
      #pragma unroll
      for (int r = 0; r < 4; ++r) {
        out[(size_t)(nn * OCc + oc + r) * HW + px] = acc[f][j][r];
      }
    }
  }
}

extern "C" void kernel_launch(void* const* d_in, const int* in_sizes, int n_in,
                              void* d_out, int out_size, void* d_ws, size_t ws_size,
                              hipStream_t stream) {
  const float* x      = (const float*)d_in[0];
  const float* offset = (const float*)d_in[1];
  const float* weight = (const float*)d_in[2];
  float* out = (float*)d_out;
  unsigned short* wp = (unsigned short*)d_ws;              // 1.18 MB
  unsigned short* xt = (unsigned short*)d_ws + XT_OFF;     // 13.1 MB

  pack_weight<<<dim3(NKB * 16 * 64 / 256), dim3(256), 0, stream>>>(weight, wp);
  nhwc_pack<<<dim3(HW / 64, Cc / 64, 4), dim3(256), 0, stream>>>(x, xt);
  dcn_mfma<<<dim3(800), dim3(256), 0, stream>>>(x, offset, wp, xt, out);
}

// Round 11
// 109.456 us; speedup vs baseline: 2.2690x; 1.1211x over previous
//
#include <hip/hip_runtime.h>

// Deformable conv2d (N=4, C=OC=256, 80x80, 3x3, s1 p1 d1):
// fused bilinear-im2col + bf16 MFMA GEMM, fp32 accumulate.
// R11: L2-bandwidth attack. PT 32->64 px/block, 8-wave 512-thr blocks,
//      400 blocks: per-block A(weight) re-read amortized over 2x pixels
//      -> total L2 read ~1.4GB -> ~0.93GB. Per-thread structure identical
//      to R10 (4 corner gathers, short8 slab write, verified XOR swizzle).
//      Issue order fixed: A-loads (mfma) BEFORE fresh gathers (vmcnt
//      retires in-order; old order made MFMA wait on just-issued gathers).

typedef short short8 __attribute__((ext_vector_type(8)));
typedef float floatx4 __attribute__((ext_vector_type(4)));

#define Cc    256
#define OCc   256
#define Hh    80
#define Ww    80
#define HW    6400
#define KK    9
#define Ktot  2304
#define PT    64            // pixels per block
#define KC    64            // K per chunk = one tap x 64 channels
#define NCHUNK (Ktot / KC)  // 36
#define NKB   (Ktot / 32)   // 72
#define WP_ELEMS (Ktot * OCc)          // 589824 ushorts (1.18 MB)
#define XT_OFF   ((size_t)WP_ELEMS)

// Relaxed barrier: retire LDS ops; vmem gathers stay in flight.
#define BARRIER_LDS()                                      \
  do {                                                     \
    asm volatile("s_waitcnt lgkmcnt(0)" ::: "memory");     \
    __builtin_amdgcn_s_barrier();                          \
  } while (0)

__device__ __forceinline__ unsigned short f2bf(float f) {
  unsigned u = __float_as_uint(f);
  u += 0x7FFF + ((u >> 16) & 1);
  return (unsigned short)(u >> 16);
}
__device__ __forceinline__ float bf2f(unsigned short u) {
  return __uint_as_float((unsigned)u << 16);
}

// ---- Kernel 1: weight fp32 -> bf16 A-fragments, tap-major K (k'=tap*256+c) --
__global__ void pack_weight(const float* __restrict__ w,
                            unsigned short* __restrict__ wp) {
  const int t = blockIdx.x * 256 + threadIdx.x;   // 73728 threads
  const int lane = t & 63;
  const int ocf  = (t >> 6) & 15;
  const int kb   = t >> 10;
  const int oc   = ocf * 16 + (lane & 15);
  const int k0   = kb * 32 + (lane >> 4) * 8;     // 8 consecutive k'
  const int tap  = k0 >> 8;
  const int c0   = k0 & 255;
  const float* src = w + (size_t)oc * Ktot + (size_t)c0 * KK + tap;
  short8 pk;
  #pragma unroll
  for (int e = 0; e < 8; ++e) pk[e] = (short)f2bf(src[e * KK]);
  *(short8*)(wp + (size_t)t * 8) = pk;
}

// ---- Kernel 2: x NCHW fp32 -> NHWC bf16 (xt[n][hw][c]) ----
__global__ void nhwc_pack(const float* __restrict__ x,
                          unsigned short* __restrict__ xt) {
  __shared__ float tile[64][65];
  const int tid = threadIdx.x;
  const int hw0 = blockIdx.x * 64;
  const int c0  = blockIdx.y * 64;
  const int n   = blockIdx.z;
  #pragma unroll
  for (int i = 0; i < 16; ++i) {
    const int idx = i * 256 + tid;
    const int cl = idx >> 6, hl = idx & 63;
    tile[cl][hl] = x[((size_t)(n * Cc + c0 + cl)) * HW + hw0 + hl];
  }
  __syncthreads();
  #pragma unroll
  for (int i = 0; i < 16; ++i) {
    const int idx = i * 256 + tid;
    const int hl = idx >> 6, cl = idx & 63;
    xt[((size_t)(n * HW + hw0 + hl)) * Cc + c0 + cl] = f2bf(tile[cl][hl]);
  }
}

// ---- Kernel 3: fused sampling + MFMA, 8 waves / 64 px per block ----
__global__ __launch_bounds__(512, 4) void dcn_mfma(
    const float* __restrict__ x, const float* __restrict__ offset,
    const unsigned short* __restrict__ wp,
    const unsigned short* __restrict__ xt, float* __restrict__ out) {
  __shared__ unsigned short s_col[3][PT * KC];  // 3 x 8KB, XOR-swizzled [px][k]
  __shared__ float4 s_w[KK * PT];               // masked corner weights (9.2KB)
  __shared__ int4   s_i[KK * PT];               // corner byte offsets   (9.2KB)

  const int tid  = threadIdx.x;
  const int lane = tid & 63;
  const int wv   = tid >> 6;        // 8 waves; wave owns ocf {2wv, 2wv+1}

  // XCD-aware bijective swizzle: 400 blocks = 8 XCDs x 50 contiguous tiles
  const int bid  = blockIdx.x;
  const int logical = (bid & 7) * 50 + (bid >> 3);
  const int nn   = logical / 100;
  const int tile = logical - nn * 100;
  const int p0   = tile * PT;
  const char* xn = (const char*)(xt + (size_t)nn * HW * Cc);

  // ---- Phase 0: bilinear coords; masks folded into per-corner weights ----
  for (int s = tid; s < KK * PT; s += 512) {
    const int k = s / PT, p = s % PT;
    const int pp = p0 + p;
    const int oy = pp / Ww, ox = pp % Ww;
    const int ky = k / 3, kx = k % 3;
    const float offy = offset[(size_t)(nn * 18 + 2 * k    ) * HW + pp];
    const float offx = offset[(size_t)(nn * 18 + 2 * k + 1) * HW + pp];
    const float py = offy + (float)(ky + oy - 1);
    const float px = offx + (float)(kx + ox - 1);
    const float fy0 = floorf(py), fx0 = floorf(px);
    const int iy0 = (int)fy0, ix0 = (int)fx0;
    const float wy1 = py - fy0, wx1 = px - fx0;
    const float wy0 = 1.f - wy1, wx0 = 1.f - wx1;
    const bool my0 = (iy0     >= 0) & (iy0     < Hh);
    const bool my1 = (iy0 + 1 >= 0) & (iy0 + 1 < Hh);
    const bool mx0 = (ix0     >= 0) & (ix0     < Ww);
    const bool mx1 = (ix0 + 1 >= 0) & (ix0 + 1 < Ww);
    const int cy0 = min(max(iy0,     0), Hh - 1);
    const int cy1 = min(max(iy0 + 1, 0), Hh - 1);
    const int cx0 = min(max(ix0,     0), Ww - 1);
    const int cx1 = min(max(ix0 + 1, 0), Ww - 1);
    float4 w4;
    w4.x = wx0 * wy0 * ((my0 && mx0) ? 1.f : 0.f);
    w4.y = wx1 * wy0 * ((my0 && mx1) ? 1.f : 0.f);
    w4.z = wx0 * wy1 * ((my1 && mx0) ? 1.f : 0.f);
    w4.w = wx1 * wy1 * ((my1 && mx1) ? 1.f : 0.f);
    int4 i4;  // byte offsets into xt[n]: hw * 256ch * 2B
    i4.x = (cy0 * Ww + cx0) * 512;  i4.y = (cy0 * Ww + cx1) * 512;
    i4.z = (cy1 * Ww + cx0) * 512;  i4.w = (cy1 * Ww + cx1) * 512;
    s_w[s] = w4;
    s_i[s] = i4;
  }

  floatx4 acc[2][4] = {};           // 2 ocf x 4 px-frags
  const int lm = lane & 15, lg = lane >> 4;
  const int spx = tid & 63;         // sampling pixel (64 per block)
  const int cg  = tid >> 6;         // channel group: 8 channels (== wv)
  const int wbyte = spx * 128 + ((cg * 16) ^ ((spx & 7) << 4));
  __syncthreads();                  // once; full drain fine here

  // Two named in-flight gather sets (16 VGPR each) — rule #20: static names.
  short8 raA, rbA, rcA, rdA, raB, rbB, rcB, rdB;

  #define ISSUE(ch, S)                                                  \
    { const int tap_ = (ch) >> 2;                                       \
      const int coff_ = (((ch) & 3) * KC + cg * 8) * 2;                 \
      const int4 i4_ = s_i[tap_ * PT + spx];                            \
      ra##S = *(const short8*)(xn + i4_.x + coff_);                     \
      rb##S = *(const short8*)(xn + i4_.y + coff_);                     \
      rc##S = *(const short8*)(xn + i4_.z + coff_);                     \
      rd##S = *(const short8*)(xn + i4_.w + coff_); }

  #define FINISH(ch, S)                                                 \
    { const int tap_ = (ch) >> 2;                                       \
      const float4 w4_ = s_w[tap_ * PT + spx];                          \
      short8 pk_;                                                       \
      _Pragma("unroll")                                                 \
      for (int e = 0; e < 8; ++e) {                                     \
        const float v_ = w4_.x * bf2f((unsigned short)ra##S[e])         \
                       + w4_.y * bf2f((unsigned short)rb##S[e])         \
                       + w4_.z * bf2f((unsigned short)rc##S[e])         \
                       + w4_.w * bf2f((unsigned short)rd##S[e]);        \
        pk_[e] = (short)f2bf(v_);                                       \
      }                                                                 \
      *(short8*)((char*)s_col[(ch) % 3] + wbyte) = pk_; }

  auto mfma_step = [&](int ch) {
    const char* base = (const char*)s_col[ch % 3];
    const int kb0 = ch * 2;
    #pragma unroll
    for (int ks = 0; ks < 2; ++ks) {
      short8 b[4];
      #pragma unroll
      for (int j = 0; j < 4; ++j) {
        const int px = j * 16 + lm;
        const int byte = px * 128 + (((ks * 64) + lg * 16) ^ ((px & 7) << 4));
        b[j] = *(const short8*)(base + byte);
      }
      const size_t abase = (size_t)(kb0 + ks) * 16 * 64 * 8;
      #pragma unroll
      for (int f = 0; f < 2; ++f) {
        const int ocf = wv * 2 + f;
        const short8 a = *(const short8*)(wp + abase + (size_t)(ocf * 64 + lane) * 8);
        #pragma unroll
        for (int j = 0; j < 4; ++j)
          acc[f][j] = __builtin_amdgcn_mfma_f32_16x16x32_bf16(a, b[j], acc[f][j], 0, 0, 0);
      }
    }
  };

  // ---- Prologue: buf0 ready; A = gathers(1) in flight ----
  ISSUE(0, A);
  FINISH(0, A);          // startup stall (once)
  ISSUE(1, A);
  BARRIER_LDS();

  // ---- Main loop. Order per chunk: MFMA(+A-loads) -> issue gathers -> finish.
  //      (A-loads precede fresh gathers in the vmcnt queue -> MFMA never
  //       transitively waits on just-issued scattered loads.)
  for (int it = 0; it < NCHUNK / 2; ++it) {
    const int ch = it * 2;
    mfma_step(ch);
    if (ch + 2 < NCHUNK) ISSUE(ch + 2, B);
    FINISH(ch + 1, A);   // gathers issued a full chunk ago
    BARRIER_LDS();
    mfma_step(ch + 1);
    if (ch + 3 < NCHUNK) ISSUE(ch + 3, A);
    if (ch + 2 < NCHUNK) FINISH(ch + 2, B);
    BARRIER_LDS();
  }

  // ---- Epilogue: direct stores; C/D col(px)=lane&15, row(oc)=lg*4+r ----
  #pragma unroll
  for (int f = 0; f < 2; ++f) {
    const int oc = (wv * 2 + f) * 16 + lg * 4;
    #pragma unroll
    for (int j = 0; j < 4; ++j) {
      const int px = p0 + j * 16 + lm;
      #pragma unroll
      for (int r = 0; r < 4; ++r) {
        out[(size_t)(nn * OCc + oc + r) * HW + px] = acc[f][j][r];
      }
    }
  }
}

extern "C" void kernel_launch(void* const* d_in, const int* in_sizes, int n_in,
                              void* d_out, int out_size, void* d_ws, size_t ws_size,
                              hipStream_t stream) {
  const float* x      = (const float*)d_in[0];
  const float* offset = (const float*)d_in[1];
  const float* weight = (const float*)d_in[2];
  float* out = (float*)d_out;
  unsigned short* wp = (unsigned short*)d_ws;              // 1.18 MB
  unsigned short* xt = (unsigned short*)d_ws + XT_OFF;     // 13.1 MB

  pack_weight<<<dim3(NKB * 16 * 64 / 256), dim3(256), 0, stream>>>(weight, wp);
  nhwc_pack<<<dim3(HW / 64, Cc / 64, 4), dim3(256), 0, stream>>>(x, xt);
  dcn_mfma<<<dim3(400), dim3(512), 0, stream>>>(x, offset, wp, xt, out);
}

// Round 12
// 86.370 us; speedup vs baseline: 2.8755x; 1.2673x over previous
//
#include <hip/hip_runtime.h>

// Deformable conv2d (N=4, C=OC=256, 80x80, 3x3, s1 p1 d1):
// fused bilinear-im2col + bf16 MFMA GEMM, fp32 accumulate.
// R12 = R11 with ONE structural change: sampling thread map puts the
//   channel-group in the LOW 3 lane bits (spx=tid>>3, cg=tid&7). The 8
//   lanes covering one pixel's 128B xt segment are now consecutive in a
//   wave -> coalesced to 1 L1 transaction per line (was 8 separate 16B
//   transactions from 8 waves). Gather TA transactions drop ~8x — the
//   R8-R11 plateau's dominant term per the transaction-count model.

typedef short short8 __attribute__((ext_vector_type(8)));
typedef float floatx4 __attribute__((ext_vector_type(4)));

#define Cc    256
#define OCc   256
#define Hh    80
#define Ww    80
#define HW    6400
#define KK    9
#define Ktot  2304
#define PT    64            // pixels per block
#define KC    64            // K per chunk = one tap x 64 channels
#define NCHUNK (Ktot / KC)  // 36
#define NKB   (Ktot / 32)   // 72
#define WP_ELEMS (Ktot * OCc)          // 589824 ushorts (1.18 MB)
#define XT_OFF   ((size_t)WP_ELEMS)

// Relaxed barrier: retire LDS ops; vmem gathers stay in flight.
#define BARRIER_LDS()                                      \
  do {                                                     \
    asm volatile("s_waitcnt lgkmcnt(0)" ::: "memory");     \
    __builtin_amdgcn_s_barrier();                          \
  } while (0)

__device__ __forceinline__ unsigned short f2bf(float f) {
  unsigned u = __float_as_uint(f);
  u += 0x7FFF + ((u >> 16) & 1);
  return (unsigned short)(u >> 16);
}
__device__ __forceinline__ float bf2f(unsigned short u) {
  return __uint_as_float((unsigned)u << 16);
}

// ---- Kernel 1: weight fp32 -> bf16 A-fragments, tap-major K (k'=tap*256+c) --
__global__ void pack_weight(const float* __restrict__ w,
                            unsigned short* __restrict__ wp) {
  const int t = blockIdx.x * 256 + threadIdx.x;   // 73728 threads
  const int lane = t & 63;
  const int ocf  = (t >> 6) & 15;
  const int kb   = t >> 10;
  const int oc   = ocf * 16 + (lane & 15);
  const int k0   = kb * 32 + (lane >> 4) * 8;     // 8 consecutive k'
  const int tap  = k0 >> 8;
  const int c0   = k0 & 255;
  const float* src = w + (size_t)oc * Ktot + (size_t)c0 * KK + tap;
  short8 pk;
  #pragma unroll
  for (int e = 0; e < 8; ++e) pk[e] = (short)f2bf(src[e * KK]);
  *(short8*)(wp + (size_t)t * 8) = pk;
}

// ---- Kernel 2: x NCHW fp32 -> NHWC bf16 (xt[n][hw][c]) ----
__global__ void nhwc_pack(const float* __restrict__ x,
                          unsigned short* __restrict__ xt) {
  __shared__ float tile[64][65];
  const int tid = threadIdx.x;
  const int hw0 = blockIdx.x * 64;
  const int c0  = blockIdx.y * 64;
  const int n   = blockIdx.z;
  #pragma unroll
  for (int i = 0; i < 16; ++i) {
    const int idx = i * 256 + tid;
    const int cl = idx >> 6, hl = idx & 63;
    tile[cl][hl] = x[((size_t)(n * Cc + c0 + cl)) * HW + hw0 + hl];
  }
  __syncthreads();
  #pragma unroll
  for (int i = 0; i < 16; ++i) {
    const int idx = i * 256 + tid;
    const int hl = idx >> 6, cl = idx & 63;
    xt[((size_t)(n * HW + hw0 + hl)) * Cc + c0 + cl] = f2bf(tile[cl][hl]);
  }
}

// ---- Kernel 3: fused sampling + MFMA, 8 waves / 64 px per block ----
__global__ __launch_bounds__(512, 4) void dcn_mfma(
    const float* __restrict__ x, const float* __restrict__ offset,
    const unsigned short* __restrict__ wp,
    const unsigned short* __restrict__ xt, float* __restrict__ out) {
  __shared__ unsigned short s_col[3][PT * KC];  // 3 x 8KB, XOR-swizzled [px][k]
  __shared__ float4 s_w[KK * PT];               // masked corner weights (9.2KB)
  __shared__ int4   s_i[KK * PT];               // corner byte offsets   (9.2KB)

  const int tid  = threadIdx.x;
  const int lane = tid & 63;
  const int wv   = tid >> 6;        // 8 waves; wave owns ocf {2wv, 2wv+1}

  // XCD-aware bijective swizzle: 400 blocks = 8 XCDs x 50 contiguous tiles
  const int bid  = blockIdx.x;
  const int logical = (bid & 7) * 50 + (bid >> 3);
  const int nn   = logical / 100;
  const int tile = logical - nn * 100;
  const int p0   = tile * PT;
  const char* xn = (const char*)(xt + (size_t)nn * HW * Cc);

  // ---- Phase 0: bilinear coords; masks folded into per-corner weights ----
  for (int s = tid; s < KK * PT; s += 512) {
    const int k = s / PT, p = s % PT;
    const int pp = p0 + p;
    const int oy = pp / Ww, ox = pp % Ww;
    const int ky = k / 3, kx = k % 3;
    const float offy = offset[(size_t)(nn * 18 + 2 * k    ) * HW + pp];
    const float offx = offset[(size_t)(nn * 18 + 2 * k + 1) * HW + pp];
    const float py = offy + (float)(ky + oy - 1);
    const float px = offx + (float)(kx + ox - 1);
    const float fy0 = floorf(py), fx0 = floorf(px);
    const int iy0 = (int)fy0, ix0 = (int)fx0;
    const float wy1 = py - fy0, wx1 = px - fx0;
    const float wy0 = 1.f - wy1, wx0 = 1.f - wx1;
    const bool my0 = (iy0     >= 0) & (iy0     < Hh);
    const bool my1 = (iy0 + 1 >= 0) & (iy0 + 1 < Hh);
    const bool mx0 = (ix0     >= 0) & (ix0     < Ww);
    const bool mx1 = (ix0 + 1 >= 0) & (ix0 + 1 < Ww);
    const int cy0 = min(max(iy0,     0), Hh - 1);
    const int cy1 = min(max(iy0 + 1, 0), Hh - 1);
    const int cx0 = min(max(ix0,     0), Ww - 1);
    const int cx1 = min(max(ix0 + 1, 0), Ww - 1);
    float4 w4;
    w4.x = wx0 * wy0 * ((my0 && mx0) ? 1.f : 0.f);
    w4.y = wx1 * wy0 * ((my0 && mx1) ? 1.f : 0.f);
    w4.z = wx0 * wy1 * ((my1 && mx0) ? 1.f : 0.f);
    w4.w = wx1 * wy1 * ((my1 && mx1) ? 1.f : 0.f);
    int4 i4;  // byte offsets into xt[n]: hw * 256ch * 2B
    i4.x = (cy0 * Ww + cx0) * 512;  i4.y = (cy0 * Ww + cx1) * 512;
    i4.z = (cy1 * Ww + cx0) * 512;  i4.w = (cy1 * Ww + cx1) * 512;
    s_w[s] = w4;
    s_i[s] = i4;
  }

  floatx4 acc[2][4] = {};           // 2 ocf x 4 px-frags
  const int lm = lane & 15, lg = lane >> 4;
  // Sampling map (THE R12 change): cg in low 3 lane bits -> the 8 lanes
  // covering one pixel's contiguous 128B xt segment are consecutive in a
  // wave and coalesce to one L1 transaction per cache line.
  const int spx = tid >> 3;         // sampling pixel (0..63)
  const int cg  = tid & 7;          // channel group: 8 channels
  const int wbyte = spx * 128 + ((cg * 16) ^ ((spx & 7) << 4));
  __syncthreads();                  // once; full drain fine here

  // Two named in-flight gather sets (16 VGPR each) — rule #20: static names.
  short8 raA, rbA, rcA, rdA, raB, rbB, rcB, rdB;

  #define ISSUE(ch, S)                                                  \
    { const int tap_ = (ch) >> 2;                                       \
      const int coff_ = (((ch) & 3) * KC + cg * 8) * 2;                 \
      const int4 i4_ = s_i[tap_ * PT + spx];                            \
      ra##S = *(const short8*)(xn + i4_.x + coff_);                     \
      rb##S = *(const short8*)(xn + i4_.y + coff_);                     \
      rc##S = *(const short8*)(xn + i4_.z + coff_);                     \
      rd##S = *(const short8*)(xn + i4_.w + coff_); }

  #define FINISH(ch, S)                                                 \
    { const int tap_ = (ch) >> 2;                                       \
      const float4 w4_ = s_w[tap_ * PT + spx];                          \
      short8 pk_;                                                       \
      _Pragma("unroll")                                                 \
      for (int e = 0; e < 8; ++e) {                                     \
        const float v_ = w4_.x * bf2f((unsigned short)ra##S[e])         \
                       + w4_.y * bf2f((unsigned short)rb##S[e])         \
                       + w4_.z * bf2f((unsigned short)rc##S[e])         \
                       + w4_.w * bf2f((unsigned short)rd##S[e]);        \
        pk_[e] = (short)f2bf(v_);                                       \
      }                                                                 \
      *(short8*)((char*)s_col[(ch) % 3] + wbyte) = pk_; }

  auto mfma_step = [&](int ch) {
    const char* base = (const char*)s_col[ch % 3];
    const int kb0 = ch * 2;
    #pragma unroll
    for (int ks = 0; ks < 2; ++ks) {
      short8 b[4];
      #pragma unroll
      for (int j = 0; j < 4; ++j) {
        const int px = j * 16 + lm;
        const int byte = px * 128 + (((ks * 64) + lg * 16) ^ ((px & 7) << 4));
        b[j] = *(const short8*)(base + byte);
      }
      const size_t abase = (size_t)(kb0 + ks) * 16 * 64 * 8;
      #pragma unroll
      for (int f = 0; f < 2; ++f) {
        const int ocf = wv * 2 + f;
        const short8 a = *(const short8*)(wp + abase + (size_t)(ocf * 64 + lane) * 8);
        #pragma unroll
        for (int j = 0; j < 4; ++j)
          acc[f][j] = __builtin_amdgcn_mfma_f32_16x16x32_bf16(a, b[j], acc[f][j], 0, 0, 0);
      }
    }
  };

  // ---- Prologue: buf0 ready; A = gathers(1) in flight ----
  ISSUE(0, A);
  FINISH(0, A);          // startup stall (once)
  ISSUE(1, A);
  BARRIER_LDS();

  // ---- Main loop: MFMA(+A-loads) -> issue gathers -> finish prev ----
  for (int it = 0; it < NCHUNK / 2; ++it) {
    const int ch = it * 2;
    mfma_step(ch);
    if (ch + 2 < NCHUNK) ISSUE(ch + 2, B);
    FINISH(ch + 1, A);   // gathers issued a full chunk ago
    BARRIER_LDS();
    mfma_step(ch + 1);
    if (ch + 3 < NCHUNK) ISSUE(ch + 3, A);
    if (ch + 2 < NCHUNK) FINISH(ch + 2, B);
    BARRIER_LDS();
  }

  // ---- Epilogue: direct stores; C/D col(px)=lane&15, row(oc)=lg*4+r ----
  #pragma unroll
  for (int f = 0; f < 2; ++f) {
    const int oc = (wv * 2 + f) * 16 + lg * 4;
    #pragma unroll
    for (int j = 0; j < 4; ++j) {
      const int px = p0 + j * 16 + lm;
      #pragma unroll
      for (int r = 0; r < 4; ++r) {
        out[(size_t)(nn * OCc + oc + r) * HW + px] = acc[f][j][r];
      }
    }
  }
}

extern "C" void kernel_launch(void* const* d_in, const int* in_sizes, int n_in,
                              void* d_out, int out_size, void* d_ws, size_t ws_size,
                              hipStream_t stream) {
  const float* x      = (const float*)d_in[0];
  const float* offset = (const float*)d_in[1];
  const float* weight = (const float*)d_in[2];
  float* out = (float*)d_out;
  unsigned short* wp = (unsigned short*)d_ws;              // 1.18 MB
  unsigned short* xt = (unsigned short*)d_ws + XT_OFF;     // 13.1 MB

  pack_weight<<<dim3(NKB * 16 * 64 / 256), dim3(256), 0, stream>>>(weight, wp);
  nhwc_pack<<<dim3(HW / 64, Cc / 64, 4), dim3(256), 0, stream>>>(x, xt);
  dcn_mfma<<<dim3(400), dim3(512), 0, stream>>>(x, offset, wp, xt, out);
}

// Round 14
// 73.860 us; speedup vs baseline: 3.3625x; 1.1694x over previous
//
#include <hip/hip_runtime.h>

// Deformable conv2d (N=4, C=OC=256, 80x80, 3x3, s1 p1 d1):
// fused bilinear-im2col + bf16 MFMA GEMM, fp32 accumulate.
// R14 = R12 (verified: NHWC xt, coalesced channel-low gathers, XCD swizzle,
//   f32 FINISH math) + double-buffered A-FRAGMENT REGISTER PREFETCH:
//   chunk ch+1's 4 A-frags (16 VGPR/set, 2 named sets) load during chunk ch,
//   so mfma_step is pure ds_read+MFMA with no global-latency head stall
//   (BARRIER_LDS's "memory" clobber had pinned A-loads after each barrier).
//   + T5 setprio around the MFMA cluster. R13's unverified perm/dot2 math
//   reverted wholesale (absmax 7.0 fail).

typedef short short8 __attribute__((ext_vector_type(8)));
typedef float floatx4 __attribute__((ext_vector_type(4)));
typedef unsigned int uint4v __attribute__((ext_vector_type(4)));

#define Cc    256
#define OCc   256
#define Hh    80
#define Ww    80
#define HW    6400
#define KK    9
#define Ktot  2304
#define PT    64            // pixels per block
#define KC    64            // K per chunk = one tap x 64 channels
#define NCHUNK (Ktot / KC)  // 36
#define NKB   (Ktot / 32)   // 72
#define WP_ELEMS (Ktot * OCc)          // 589824 ushorts (1.18 MB)
#define XT_OFF   ((size_t)WP_ELEMS)

// Relaxed barrier: retire LDS ops; vmem loads stay in flight.
#define BARRIER_LDS()                                      \
  do {                                                     \
    asm volatile("s_waitcnt lgkmcnt(0)" ::: "memory");     \
    __builtin_amdgcn_s_barrier();                          \
  } while (0)

__device__ __forceinline__ unsigned short f2bf(float f) {
  unsigned u = __float_as_uint(f);
  u += 0x7FFF + ((u >> 16) & 1);
  return (unsigned short)(u >> 16);
}
__device__ __forceinline__ float bf2f(unsigned short u) {
  return __uint_as_float((unsigned)u << 16);
}

// ---- Kernel 1: weight fp32 -> bf16 A-fragments, tap-major K (k'=tap*256+c) --
__global__ void pack_weight(const float* __restrict__ w,
                            unsigned short* __restrict__ wp) {
  const int t = blockIdx.x * 256 + threadIdx.x;   // 73728 threads
  const int lane = t & 63;
  const int ocf  = (t >> 6) & 15;
  const int kb   = t >> 10;
  const int oc   = ocf * 16 + (lane & 15);
  const int k0   = kb * 32 + (lane >> 4) * 8;     // 8 consecutive k'
  const int tap  = k0 >> 8;
  const int c0   = k0 & 255;
  const float* src = w + (size_t)oc * Ktot + (size_t)c0 * KK + tap;
  short8 pk;
  #pragma unroll
  for (int e = 0; e < 8; ++e) pk[e] = (short)f2bf(src[e * KK]);
  *(short8*)(wp + (size_t)t * 8) = pk;
}

// ---- Kernel 2: x NCHW fp32 -> NHWC bf16 (xt[n][hw][c]) ----
__global__ void nhwc_pack(const float* __restrict__ x,
                          unsigned short* __restrict__ xt) {
  __shared__ float tile[64][65];
  const int tid = threadIdx.x;
  const int hw0 = blockIdx.x * 64;
  const int c0  = blockIdx.y * 64;
  const int n   = blockIdx.z;
  #pragma unroll
  for (int i = 0; i < 16; ++i) {
    const int idx = i * 256 + tid;
    const int cl = idx >> 6, hl = idx & 63;
    tile[cl][hl] = x[((size_t)(n * Cc + c0 + cl)) * HW + hw0 + hl];
  }
  __syncthreads();
  #pragma unroll
  for (int i = 0; i < 16; ++i) {
    const int idx = i * 256 + tid;
    const int hl = idx >> 6, cl = idx & 63;
    xt[((size_t)(n * HW + hw0 + hl)) * Cc + c0 + cl] = f2bf(tile[cl][hl]);
  }
}

// ---- Kernel 3: fused sampling + MFMA, 8 waves / 64 px per block ----
__global__ __launch_bounds__(512, 4) void dcn_mfma(
    const float* __restrict__ x, const float* __restrict__ offset,
    const unsigned short* __restrict__ wp,
    const unsigned short* __restrict__ xt, float* __restrict__ out) {
  __shared__ unsigned short s_col[3][PT * KC];  // 3 x 8KB, XOR-swizzled [px][k]
  __shared__ float4 s_w[KK * PT];               // masked corner weights
  __shared__ int4   s_i[KK * PT];               // corner byte offsets (hw*512)

  const int tid  = threadIdx.x;
  const int lane = tid & 63;
  const int wv   = tid >> 6;        // 8 waves; wave owns ocf {2wv, 2wv+1}

  // XCD-aware bijective swizzle: 400 blocks = 8 XCDs x 50 contiguous tiles
  const int bid  = blockIdx.x;
  const int logical = (bid & 7) * 50 + (bid >> 3);
  const int nn   = logical / 100;
  const int tile = logical - nn * 100;
  const int p0   = tile * PT;
  const char* xn = (const char*)(xt + (size_t)nn * HW * Cc);

  // ---- Phase 0: bilinear coords; masks folded into per-corner weights ----
  for (int s = tid; s < KK * PT; s += 512) {
    const int k = s / PT, p = s % PT;
    const int pp = p0 + p;
    const int oy = pp / Ww, ox = pp % Ww;
    const int ky = k / 3, kx = k % 3;
    const float offy = offset[(size_t)(nn * 18 + 2 * k    ) * HW + pp];
    const float offx = offset[(size_t)(nn * 18 + 2 * k + 1) * HW + pp];
    const float py = offy + (float)(ky + oy - 1);
    const float px = offx + (float)(kx + ox - 1);
    const float fy0 = floorf(py), fx0 = floorf(px);
    const int iy0 = (int)fy0, ix0 = (int)fx0;
    const float wy1 = py - fy0, wx1 = px - fx0;
    const float wy0 = 1.f - wy1, wx0 = 1.f - wx1;
    const bool my0 = (iy0     >= 0) & (iy0     < Hh);
    const bool my1 = (iy0 + 1 >= 0) & (iy0 + 1 < Hh);
    const bool mx0 = (ix0     >= 0) & (ix0     < Ww);
    const bool mx1 = (ix0 + 1 >= 0) & (ix0 + 1 < Ww);
    const int cy0 = min(max(iy0,     0), Hh - 1);
    const int cy1 = min(max(iy0 + 1, 0), Hh - 1);
    const int cx0 = min(max(ix0,     0), Ww - 1);
    const int cx1 = min(max(ix0 + 1, 0), Ww - 1);
    float4 w4;
    w4.x = wx0 * wy0 * ((my0 && mx0) ? 1.f : 0.f);
    w4.y = wx1 * wy0 * ((my0 && mx1) ? 1.f : 0.f);
    w4.z = wx0 * wy1 * ((my1 && mx0) ? 1.f : 0.f);
    w4.w = wx1 * wy1 * ((my1 && mx1) ? 1.f : 0.f);
    int4 i4;  // byte offsets into xt[n]: hw * 256ch * 2B
    i4.x = (cy0 * Ww + cx0) * 512;  i4.y = (cy0 * Ww + cx1) * 512;
    i4.z = (cy1 * Ww + cx0) * 512;  i4.w = (cy1 * Ww + cx1) * 512;
    s_w[s] = w4;
    s_i[s] = i4;
  }

  floatx4 acc[2][4] = {};           // 2 ocf x 4 px-frags
  const int lm = lane & 15, lg = lane >> 4;
  // Coalesced sampling map (R12): cg in low 3 lane bits.
  const int spx = tid >> 3;         // sampling pixel (0..63)
  const int cg  = tid & 7;          // channel group: 8 channels
  const int wbyte = spx * 128 + ((cg * 16) ^ ((spx & 7) << 4));
  __syncthreads();                  // once; full drain fine here

  // Named in-flight register sets (rule #20: static names).
  short8 raA, rbA, rcA, rdA, raB, rbB, rcB, rdB;     // gathers (2 sets)
  short8 fA00, fA01, fA10, fA11, fB00, fB01, fB10, fB11;  // A-frags (2 sets)

  #define ISSUE(ch, S)                                                  \
    { const int tap_ = (ch) >> 2;                                       \
      const int coff_ = (((ch) & 3) * KC + cg * 8) * 2;                 \
      const int4 i4_ = s_i[tap_ * PT + spx];                            \
      ra##S = *(const short8*)(xn + i4_.x + coff_);                     \
      rb##S = *(const short8*)(xn + i4_.y + coff_);                     \
      rc##S = *(const short8*)(xn + i4_.z + coff_);                     \
      rd##S = *(const short8*)(xn + i4_.w + coff_); }

  // Prefetch chunk ch's 4 A-fragments (2 ocf x 2 ks) into register set S.
  #define PREFA(ch, S)                                                  \
    { const unsigned short* w0_ = wp + (size_t)((ch) * 2) * (16 * 64 * 8) \
                                     + (size_t)((wv * 2) * 64 + lane) * 8; \
      f##S##00 = *(const short8*)(w0_);                                 \
      f##S##01 = *(const short8*)(w0_ + 64 * 8);                        \
      f##S##10 = *(const short8*)(w0_ + 16 * 64 * 8);                   \
      f##S##11 = *(const short8*)(w0_ + 16 * 64 * 8 + 64 * 8); }

  #define FINISH(ch, S)                                                 \
    { const int tap_ = (ch) >> 2;                                       \
      const float4 w4_ = s_w[tap_ * PT + spx];                          \
      short8 pk_;                                                       \
      _Pragma("unroll")                                                 \
      for (int e = 0; e < 8; ++e) {                                     \
        const float v_ = w4_.x * bf2f((unsigned short)ra##S[e])         \
                       + w4_.y * bf2f((unsigned short)rb##S[e])         \
                       + w4_.z * bf2f((unsigned short)rc##S[e])         \
                       + w4_.w * bf2f((unsigned short)rd##S[e]);        \
        pk_[e] = (short)f2bf(v_);                                       \
      }                                                                 \
      *(short8*)((char*)s_col[(ch) % 3] + wbyte) = pk_; }

  // Pure ds_read + MFMA (A-frags preloaded in set S) + T5 setprio.
  #define MFMA_STEP(ch, S)                                              \
    { const char* base_ = (const char*)s_col[(ch) % 3];                 \
      __builtin_amdgcn_s_setprio(1);                                    \
      _Pragma("unroll")                                                 \
      for (int ks = 0; ks < 2; ++ks) {                                  \
        short8 b_[4];                                                   \
        _Pragma("unroll")                                               \
        for (int j = 0; j < 4; ++j) {                                   \
          const int px_ = j * 16 + lm;                                  \
          const int byte_ = px_ * 128 + (((ks * 64) + lg * 16) ^ ((px_ & 7) << 4)); \
          b_[j] = *(const short8*)(base_ + byte_);                      \
        }                                                               \
        const short8 a0_ = ks ? f##S##10 : f##S##00;                    \
        const short8 a1_ = ks ? f##S##11 : f##S##01;                    \
        _Pragma("unroll")                                               \
        for (int j = 0; j < 4; ++j)                                     \
          acc[0][j] = __builtin_amdgcn_mfma_f32_16x16x32_bf16(a0_, b_[j], acc[0][j], 0, 0, 0); \
        _Pragma("unroll")                                               \
        for (int j = 0; j < 4; ++j)                                     \
          acc[1][j] = __builtin_amdgcn_mfma_f32_16x16x32_bf16(a1_, b_[j], acc[1][j], 0, 0, 0); \
      }                                                                 \
      __builtin_amdgcn_s_setprio(0); }

  // ---- Prologue: buf0 + A-frags(0) ready; gathers(1) in flight ----
  PREFA(0, A);
  ISSUE(0, A);
  FINISH(0, A);          // startup stall (once)
  ISSUE(1, A);
  BARRIER_LDS();

  // ---- Main loop (2 chunks/iter). Per half: MFMA (preloaded A) ->
  //      issue next gathers -> prefetch next A -> finish prev -> barrier.
  for (int it = 0; it < NCHUNK / 2; ++it) {
    const int ch = it * 2;
    MFMA_STEP(ch, A);
    if (ch + 2 < NCHUNK) ISSUE(ch + 2, B);
    PREFA(ch + 1, B);
    FINISH(ch + 1, A);   // gathers issued a full chunk ago
    BARRIER_LDS();
    MFMA_STEP(ch + 1, B);
    if (ch + 3 < NCHUNK) ISSUE(ch + 3, A);
    if (ch + 2 < NCHUNK) { PREFA(ch + 2, A); FINISH(ch + 2, B); }
    BARRIER_LDS();
  }

  // ---- Epilogue: direct stores; C/D col(px)=lane&15, row(oc)=lg*4+r ----
  #pragma unroll
  for (int f = 0; f < 2; ++f) {
    const int oc = (wv * 2 + f) * 16 + lg * 4;
    #pragma unroll
    for (int j = 0; j < 4; ++j) {
      const int px = p0 + j * 16 + lm;
      #pragma unroll
      for (int r = 0; r < 4; ++r) {
        out[(size_t)(nn * OCc + oc + r) * HW + px] = acc[f][j][r];
      }
    }
  }
}

extern "C" void kernel_launch(void* const* d_in, const int* in_sizes, int n_in,
                              void* d_out, int out_size, void* d_ws, size_t ws_size,
                              hipStream_t stream) {
  const float* x      = (const float*)d_in[0];
  const float* offset = (const float*)d_in[1];
  const float* weight = (const float*)d_in[2];
  float* out = (float*)d_out;
  unsigned short* wp = (unsigned short*)d_ws;              // 1.18 MB
  unsigned short* xt = (unsigned short*)d_ws + XT_OFF;     // 13.1 MB

  pack_weight<<<dim3(NKB * 16 * 64 / 256), dim3(256), 0, stream>>>(weight, wp);
  nhwc_pack<<<dim3(HW / 64, Cc / 64, 4), dim3(256), 0, stream>>>(x, xt);
  dcn_mfma<<<dim3(400), dim3(512), 0, stream>>>(x, offset, wp, xt, out);
}

// Round 15
// 72.082 us; speedup vs baseline: 3.4455x; 1.0247x over previous
//
#include <hip/hip_runtime.h>

// Deformable conv2d (N=4, C=OC=256, 80x80, 3x3, s1 p1 d1):
// fused bilinear-im2col + bf16 MFMA GEMM, fp32 accumulate.
// R15 = R14 + two fixes:
//  (a) PREFA issued BEFORE ISSUE in each half-iteration. vmcnt retires
//      in-order; R14 issued A-frags LAST, so MFMA's A-wait was vmcnt(0),
//      draining all in-flight gathers every chunk (silent depth-0 pipeline).
//      Now A-frags are older: MFMA waits vmcnt(4), gathers keep flying.
//  (b) FINISH pack via v_cvt_pk_bf16_f32 (verified semantics: lo16=bf16(s0),
//      hi16=bf16(s1)) -- replaces 8x manual-RNE f2bf (~32 ops) with 4 ops.

typedef short short8 __attribute__((ext_vector_type(8)));
typedef float floatx4 __attribute__((ext_vector_type(4)));
typedef unsigned int uint4v __attribute__((ext_vector_type(4)));

#define Cc    256
#define OCc   256
#define Hh    80
#define Ww    80
#define HW    6400
#define KK    9
#define Ktot  2304
#define PT    64            // pixels per block
#define KC    64            // K per chunk = one tap x 64 channels
#define NCHUNK (Ktot / KC)  // 36
#define NKB   (Ktot / 32)   // 72
#define WP_ELEMS (Ktot * OCc)          // 589824 ushorts (1.18 MB)
#define XT_OFF   ((size_t)WP_ELEMS)

// Relaxed barrier: retire LDS ops; vmem loads stay in flight.
#define BARRIER_LDS()                                      \
  do {                                                     \
    asm volatile("s_waitcnt lgkmcnt(0)" ::: "memory");     \
    __builtin_amdgcn_s_barrier();                          \
  } while (0)

__device__ __forceinline__ unsigned short f2bf(float f) {
  unsigned u = __float_as_uint(f);
  u += 0x7FFF + ((u >> 16) & 1);
  return (unsigned short)(u >> 16);
}
__device__ __forceinline__ float bf2f(unsigned short u) {
  return __uint_as_float((unsigned)u << 16);
}
// lo16 = bf16(lo), hi16 = bf16(hi)  (RNE; T12/m240-verified on gfx950)
__device__ __forceinline__ unsigned int cvtpk(float lo, float hi) {
  unsigned int r;
  asm("v_cvt_pk_bf16_f32 %0, %1, %2" : "=v"(r) : "v"(lo), "v"(hi));
  return r;
}

// ---- Kernel 1: weight fp32 -> bf16 A-fragments, tap-major K (k'=tap*256+c) --
__global__ void pack_weight(const float* __restrict__ w,
                            unsigned short* __restrict__ wp) {
  const int t = blockIdx.x * 256 + threadIdx.x;   // 73728 threads
  const int lane = t & 63;
  const int ocf  = (t >> 6) & 15;
  const int kb   = t >> 10;
  const int oc   = ocf * 16 + (lane & 15);
  const int k0   = kb * 32 + (lane >> 4) * 8;     // 8 consecutive k'
  const int tap  = k0 >> 8;
  const int c0   = k0 & 255;
  const float* src = w + (size_t)oc * Ktot + (size_t)c0 * KK + tap;
  short8 pk;
  #pragma unroll
  for (int e = 0; e < 8; ++e) pk[e] = (short)f2bf(src[e * KK]);
  *(short8*)(wp + (size_t)t * 8) = pk;
}

// ---- Kernel 2: x NCHW fp32 -> NHWC bf16 (xt[n][hw][c]) ----
__global__ void nhwc_pack(const float* __restrict__ x,
                          unsigned short* __restrict__ xt) {
  __shared__ float tile[64][65];
  const int tid = threadIdx.x;
  const int hw0 = blockIdx.x * 64;
  const int c0  = blockIdx.y * 64;
  const int n   = blockIdx.z;
  #pragma unroll
  for (int i = 0; i < 16; ++i) {
    const int idx = i * 256 + tid;
    const int cl = idx >> 6, hl = idx & 63;
    tile[cl][hl] = x[((size_t)(n * Cc + c0 + cl)) * HW + hw0 + hl];
  }
  __syncthreads();
  #pragma unroll
  for (int i = 0; i < 16; ++i) {
    const int idx = i * 256 + tid;
    const int hl = idx >> 6, cl = idx & 63;
    xt[((size_t)(n * HW + hw0 + hl)) * Cc + c0 + cl] = f2bf(tile[cl][hl]);
  }
}

// ---- Kernel 3: fused sampling + MFMA, 8 waves / 64 px per block ----
__global__ __launch_bounds__(512, 4) void dcn_mfma(
    const float* __restrict__ x, const float* __restrict__ offset,
    const unsigned short* __restrict__ wp,
    const unsigned short* __restrict__ xt, float* __restrict__ out) {
  __shared__ unsigned short s_col[3][PT * KC];  // 3 x 8KB, XOR-swizzled [px][k]
  __shared__ float4 s_w[KK * PT];               // masked corner weights
  __shared__ int4   s_i[KK * PT];               // corner byte offsets (hw*512)

  const int tid  = threadIdx.x;
  const int lane = tid & 63;
  const int wv   = tid >> 6;        // 8 waves; wave owns ocf {2wv, 2wv+1}

  // XCD-aware bijective swizzle: 400 blocks = 8 XCDs x 50 contiguous tiles
  const int bid  = blockIdx.x;
  const int logical = (bid & 7) * 50 + (bid >> 3);
  const int nn   = logical / 100;
  const int tile = logical - nn * 100;
  const int p0   = tile * PT;
  const char* xn = (const char*)(xt + (size_t)nn * HW * Cc);

  // ---- Phase 0: bilinear coords; masks folded into per-corner weights ----
  for (int s = tid; s < KK * PT; s += 512) {
    const int k = s / PT, p = s % PT;
    const int pp = p0 + p;
    const int oy = pp / Ww, ox = pp % Ww;
    const int ky = k / 3, kx = k % 3;
    const float offy = offset[(size_t)(nn * 18 + 2 * k    ) * HW + pp];
    const float offx = offset[(size_t)(nn * 18 + 2 * k + 1) * HW + pp];
    const float py = offy + (float)(ky + oy - 1);
    const float px = offx + (float)(kx + ox - 1);
    const float fy0 = floorf(py), fx0 = floorf(px);
    const int iy0 = (int)fy0, ix0 = (int)fx0;
    const float wy1 = py - fy0, wx1 = px - fx0;
    const float wy0 = 1.f - wy1, wx0 = 1.f - wx1;
    const bool my0 = (iy0     >= 0) & (iy0     < Hh);
    const bool my1 = (iy0 + 1 >= 0) & (iy0 + 1 < Hh);
    const bool mx0 = (ix0     >= 0) & (ix0     < Ww);
    const bool mx1 = (ix0 + 1 >= 0) & (ix0 + 1 < Ww);
    const int cy0 = min(max(iy0,     0), Hh - 1);
    const int cy1 = min(max(iy0 + 1, 0), Hh - 1);
    const int cx0 = min(max(ix0,     0), Ww - 1);
    const int cx1 = min(max(ix0 + 1, 0), Ww - 1);
    float4 w4;
    w4.x = wx0 * wy0 * ((my0 && mx0) ? 1.f : 0.f);
    w4.y = wx1 * wy0 * ((my0 && mx1) ? 1.f : 0.f);
    w4.z = wx0 * wy1 * ((my1 && mx0) ? 1.f : 0.f);
    w4.w = wx1 * wy1 * ((my1 && mx1) ? 1.f : 0.f);
    int4 i4;  // byte offsets into xt[n]: hw * 256ch * 2B
    i4.x = (cy0 * Ww + cx0) * 512;  i4.y = (cy0 * Ww + cx1) * 512;
    i4.z = (cy1 * Ww + cx0) * 512;  i4.w = (cy1 * Ww + cx1) * 512;
    s_w[s] = w4;
    s_i[s] = i4;
  }

  floatx4 acc[2][4] = {};           // 2 ocf x 4 px-frags
  const int lm = lane & 15, lg = lane >> 4;
  // Coalesced sampling map (R12): cg in low 3 lane bits.
  const int spx = tid >> 3;         // sampling pixel (0..63)
  const int cg  = tid & 7;          // channel group: 8 channels
  const int wbyte = spx * 128 + ((cg * 16) ^ ((spx & 7) << 4));
  __syncthreads();                  // once; full drain fine here

  // Named in-flight register sets (rule #20: static names).
  short8 raA, rbA, rcA, rdA, raB, rbB, rcB, rdB;          // gathers (2 sets)
  short8 fA00, fA01, fA10, fA11, fB00, fB01, fB10, fB11;  // A-frags (2 sets)

  #define ISSUE(ch, S)                                                  \
    { const int tap_ = (ch) >> 2;                                       \
      const int coff_ = (((ch) & 3) * KC + cg * 8) * 2;                 \
      const int4 i4_ = s_i[tap_ * PT + spx];                            \
      ra##S = *(const short8*)(xn + i4_.x + coff_);                     \
      rb##S = *(const short8*)(xn + i4_.y + coff_);                     \
      rc##S = *(const short8*)(xn + i4_.z + coff_);                     \
      rd##S = *(const short8*)(xn + i4_.w + coff_); }

  // Prefetch chunk ch's 4 A-fragments (2 ocf x 2 ks) into register set S.
  #define PREFA(ch, S)                                                  \
    { const unsigned short* w0_ = wp + (size_t)((ch) * 2) * (16 * 64 * 8) \
                                     + (size_t)((wv * 2) * 64 + lane) * 8; \
      f##S##00 = *(const short8*)(w0_);                                 \
      f##S##01 = *(const short8*)(w0_ + 64 * 8);                        \
      f##S##10 = *(const short8*)(w0_ + 16 * 64 * 8);                   \
      f##S##11 = *(const short8*)(w0_ + 16 * 64 * 8 + 64 * 8); }

  #define FINISH(ch, S)                                                 \
    { const int tap_ = (ch) >> 2;                                       \
      const float4 w4_ = s_w[tap_ * PT + spx];                          \
      float v_[8];                                                      \
      _Pragma("unroll")                                                 \
      for (int e = 0; e < 8; ++e) {                                     \
        v_[e] = w4_.x * bf2f((unsigned short)ra##S[e])                  \
              + w4_.y * bf2f((unsigned short)rb##S[e])                  \
              + w4_.z * bf2f((unsigned short)rc##S[e])                  \
              + w4_.w * bf2f((unsigned short)rd##S[e]);                 \
      }                                                                 \
      uint4v pk_;                                                       \
      _Pragma("unroll")                                                 \
      for (int r = 0; r < 4; ++r) pk_[r] = cvtpk(v_[2 * r], v_[2 * r + 1]); \
      *(uint4v*)((char*)s_col[(ch) % 3] + wbyte) = pk_; }

  // Pure ds_read + MFMA (A-frags preloaded in set S) + T5 setprio.
  #define MFMA_STEP(ch, S)                                              \
    { const char* base_ = (const char*)s_col[(ch) % 3];                 \
      __builtin_amdgcn_s_setprio(1);                                    \
      _Pragma("unroll")                                                 \
      for (int ks = 0; ks < 2; ++ks) {                                  \
        short8 b_[4];                                                   \
        _Pragma("unroll")                                               \
        for (int j = 0; j < 4; ++j) {                                   \
          const int px_ = j * 16 + lm;                                  \
          const int byte_ = px_ * 128 + (((ks * 64) + lg * 16) ^ ((px_ & 7) << 4)); \
          b_[j] = *(const short8*)(base_ + byte_);                      \
        }                                                               \
        const short8 a0_ = ks ? f##S##10 : f##S##00;                    \
        const short8 a1_ = ks ? f##S##11 : f##S##01;                    \
        _Pragma("unroll")                                               \
        for (int j = 0; j < 4; ++j)                                     \
          acc[0][j] = __builtin_amdgcn_mfma_f32_16x16x32_bf16(a0_, b_[j], acc[0][j], 0, 0, 0); \
        _Pragma("unroll")                                               \
        for (int j = 0; j < 4; ++j)                                     \
          acc[1][j] = __builtin_amdgcn_mfma_f32_16x16x32_bf16(a1_, b_[j], acc[1][j], 0, 0, 0); \
      }                                                                 \
      __builtin_amdgcn_s_setprio(0); }

  // ---- Prologue: buf0 + A-frags(0) ready; gathers(1) in flight ----
  PREFA(0, A);
  ISSUE(0, A);
  FINISH(0, A);          // startup stall (once)
  ISSUE(1, A);
  BARRIER_LDS();

  // ---- Main loop (2 chunks/iter). Per half: MFMA (A preloaded, waits
  //      vmcnt(4) -- gathers stay in flight) -> PREFA next A (older than
  //      next gathers) -> ISSUE next gathers -> FINISH prev -> barrier.
  for (int it = 0; it < NCHUNK / 2; ++it) {
    const int ch = it * 2;
    MFMA_STEP(ch, A);
    PREFA(ch + 1, B);
    if (ch + 2 < NCHUNK) ISSUE(ch + 2, B);
    FINISH(ch + 1, A);   // gathers issued a full chunk ago; waits vmcnt(8)
    BARRIER_LDS();
    MFMA_STEP(ch + 1, B);
    if (ch + 2 < NCHUNK) PREFA(ch + 2, A);
    if (ch + 3 < NCHUNK) ISSUE(ch + 3, A);
    if (ch + 2 < NCHUNK) FINISH(ch + 2, B);
    BARRIER_LDS();
  }

  // ---- Epilogue: direct stores; C/D col(px)=lane&15, row(oc)=lg*4+r ----
  #pragma unroll
  for (int f = 0; f < 2; ++f) {
    const int oc = (wv * 2 + f) * 16 + lg * 4;
    #pragma unroll
    for (int j = 0; j < 4; ++j) {
      const int px = p0 + j * 16 + lm;
      #pragma unroll
      for (int r = 0; r < 4; ++r) {
        out[(size_t)(nn * OCc + oc + r) * HW + px] = acc[f][j][r];
      }
    }
  }
}

extern "C" void kernel_launch(void* const* d_in, const int* in_sizes, int n_in,
                              void* d_out, int out_size, void* d_ws, size_t ws_size,
                              hipStream_t stream) {
  const float* x      = (const float*)d_in[0];
  const float* offset = (const float*)d_in[1];
  const float* weight = (const float*)d_in[2];
  float* out = (float*)d_out;
  unsigned short* wp = (unsigned short*)d_ws;              // 1.18 MB
  unsigned short* xt = (unsigned short*)d_ws + XT_OFF;     // 13.1 MB

  pack_weight<<<dim3(NKB * 16 * 64 / 256), dim3(256), 0, stream>>>(weight, wp);
  nhwc_pack<<<dim3(HW / 64, Cc / 64, 4), dim3(256), 0, stream>>>(x, xt);
  dcn_mfma<<<dim3(400), dim3(512), 0, stream>>>(x, offset, wp, xt, out);
}